// Round 6
// baseline (629.108 us; speedup 1.0000x reference)
//
#include <hip/hip_runtime.h>
#include <hip/hip_bf16.h>
#include <stdint.h>

#define N_NODES 20000
#define E_EDGES 320000
#define IN_F    128
#define HIDF    256
#define R_REL   4
#define NRKEYS  (N_NODES*R_REL)   // 80000
#define SCAN_BLOCKS 80            // 80*1024 = 81920 >= NRKEYS

typedef __attribute__((ext_vector_type(8))) short  short8;
typedef __attribute__((ext_vector_type(4))) float  floatx4;

__device__ __forceinline__ float bf2f(__hip_bfloat16 v){ return __bfloat162float(v); }
__device__ __forceinline__ __hip_bfloat16 f2bf(float v){ return __float2bfloat16(v); }
__device__ __forceinline__ float bfbits2f(unsigned short u){ return __uint_as_float(((unsigned)u)<<16); }

// ---------------- CSR build ----------------
__global__ void count_kernel(const int* __restrict__ ei, const int* __restrict__ et,
                             int* __restrict__ cnt)
{
    int e = blockIdx.x*256 + threadIdx.x;
    if (e >= E_EDGES) return;
    int dst = ei[E_EDGES + e];
    atomicAdd(&cnt[dst*R_REL + et[e]], 1);
}

// 3-phase parallel exclusive scan over cnt[NRKEYS] -> row_ptr, cursor
__global__ __launch_bounds__(1024) void scan_reduce_kernel(const int* __restrict__ cnt,
                                                           int* __restrict__ blocksum)
{
    int ix = blockIdx.x*1024 + threadIdx.x;
    int v = (ix < NRKEYS) ? cnt[ix] : 0;
    #pragma unroll
    for (int o=32;o>0;o>>=1) v += __shfl_xor(v, o, 64);
    __shared__ int wsum[16];
    int wave = threadIdx.x >> 6, lane = threadIdx.x & 63;
    if (lane == 0) wsum[wave] = v;
    __syncthreads();
    if (threadIdx.x == 0) {
        int s = 0;
        #pragma unroll
        for (int w=0;w<16;w++) s += wsum[w];
        blocksum[blockIdx.x] = s;
    }
}

__global__ __launch_bounds__(128) void scan_sums_kernel(const int* __restrict__ blocksum,
                                                        int* __restrict__ blockoff)
{
    __shared__ int s[128];
    int t = threadIdx.x;
    int v = (t < SCAN_BLOCKS) ? blocksum[t] : 0;
    s[t] = v; __syncthreads();
    for (int off=1; off<128; off<<=1) {
        int u = (t>=off) ? s[t-off] : 0;
        __syncthreads();
        s[t] += u;
        __syncthreads();
    }
    if (t < SCAN_BLOCKS) blockoff[t] = s[t] - v;   // exclusive
}

__global__ __launch_bounds__(1024) void scan_apply_kernel(const int* __restrict__ cnt,
                                                          const int* __restrict__ blockoff,
                                                          int* __restrict__ row_ptr,
                                                          int* __restrict__ cursor)
{
    __shared__ int s[1024];
    int t = threadIdx.x;
    int ix = blockIdx.x*1024 + t;
    int v = (ix < NRKEYS) ? cnt[ix] : 0;
    s[t] = v; __syncthreads();
    for (int off=1; off<1024; off<<=1) {
        int u = (t>=off) ? s[t-off] : 0;
        __syncthreads();
        s[t] += u;
        __syncthreads();
    }
    if (ix < NRKEYS) {
        int excl = blockoff[blockIdx.x] + s[t] - v;
        row_ptr[ix] = excl;
        cursor[ix]  = excl;
        if (ix == NRKEYS-1) row_ptr[NRKEYS] = excl + v;
    }
}

// records BOTH endpoints per CSR position so downstream kernels are
// position-indexed (round-5 bug: score was edge-id-indexed, agg read positions)
__global__ void fill_kernel(const int* __restrict__ ei, const int* __restrict__ et,
                            int* __restrict__ cursor,
                            int* __restrict__ csr_src, int* __restrict__ csr_dst)
{
    int e = blockIdx.x*256 + threadIdx.x;
    if (e >= E_EDGES) return;
    int src = ei[e];
    int dst = ei[E_EDGES + e];
    int key = dst*R_REL + et[e];
    int pos = atomicAdd(&cursor[key], 1);
    csr_src[pos] = src;
    csr_dst[pos] = dst;
}

// ---------------- weight prep: fp32 sources -> bf16 B^T = [Nout][K] ----------------
__global__ void make_b1t(const float* __restrict__ root1,
                         const float* __restrict__ W1,
                         __hip_bfloat16* __restrict__ B1t)
{
    int idx = blockIdx.x*256 + threadIdx.x;         // n*640 + k
    if (idx >= 256*640) return;
    int n = idx / 640, k = idx % 640;
    float v;
    if (k < 128) v = root1[k*256 + n];
    else         v = W1[(k-128)*256 + n];           // W1 contiguous [R*128][256]
    B1t[idx] = f2bf(v);
}

__global__ void make_b2t(const float* __restrict__ root2,
                         const float* __restrict__ W2,
                         __hip_bfloat16* __restrict__ B2t)
{
    int idx = blockIdx.x*256 + threadIdx.x;         // n*1280 + k
    if (idx >= 256*1280) return;
    int n = idx / 1280, k = idx % 1280;
    float v;
    if (k < 256) v = root2[k*256 + n];
    else         v = W2[(k-256)*256 + n];           // W2 contiguous [R*256][256]
    B2t[idx] = f2bf(v);
}

__global__ void make_b3t(const float* __restrict__ Wq, const float* __restrict__ Wk,
                         const float* __restrict__ Wv, const float* __restrict__ Wsk,
                         const float* __restrict__ bq, const float* __restrict__ bk,
                         const float* __restrict__ bv, const float* __restrict__ bsk,
                         __hip_bfloat16* __restrict__ B3t, float* __restrict__ bias3)
{
    int idx = blockIdx.x*256 + threadIdx.x;         // n*256 + k, n<1024
    if (idx >= 1024*256) return;
    int n = idx / 256, k = idx % 256;
    int g = n >> 8, nn = n & 255;
    const float* W = (g==0)?Wq:(g==1)?Wk:(g==2)?Wv:Wsk;
    B3t[idx] = f2bf(W[k*256 + nn]);
    if (k == 0) {
        const float* B = (g==0)?bq:(g==1)?bk:(g==2)?bv:bsk;
        bias3[n] = B[nn];
    }
}

// generic fp32 -> bf16 elementwise convert (layout-preserving)
__global__ void cvt_f32_bf16(const float* __restrict__ in, __hip_bfloat16* __restrict__ out, int n)
{
    int i = blockIdx.x*256 + threadIdx.x;
    if (i < n) out[i] = f2bf(in[i]);
}

// ---------------- RGCN aggregation (gather, no atomics) ----------------
__global__ __launch_bounds__(128) void agg1_kernel(const float* __restrict__ x,
                                                   const int* __restrict__ row_ptr,
                                                   const int* __restrict__ csr_src,
                                                   __hip_bfloat16* __restrict__ A1)
{
    int b = blockIdx.x;           // i*4 + r
    int i = b >> 2, r = b & 3;
    int f = threadIdx.x;          // 0..127
    int e0 = row_ptr[b], e1 = row_ptr[b+1];
    float s = 0.f;
    for (int e=e0; e<e1; e++) {
        int sidx = csr_src[e];
        s += x[(size_t)sidx*IN_F + f];
    }
    float inv = (e1>e0) ? 1.f/(float)(e1-e0) : 0.f;
    A1[(size_t)i*640 + 128 + r*128 + f] = f2bf(s*inv);
    if (r == 0) A1[(size_t)i*640 + f] = f2bf(x[(size_t)i*IN_F + f]);
}

__global__ __launch_bounds__(256) void agg2_kernel(const int* __restrict__ row_ptr,
                                                   const int* __restrict__ csr_src,
                                                   __hip_bfloat16* __restrict__ A2)
{
    int b = blockIdx.x;
    int i = b >> 2, r = b & 3;
    int f = threadIdx.x;          // 0..255
    int e0 = row_ptr[b], e1 = row_ptr[b+1];
    float s = 0.f;
    for (int e=e0; e<e1; e++) {
        int sidx = csr_src[e];
        s += bf2f(A2[(size_t)sidx*1280 + f]);   // cols 0..255 hold h1
    }
    float inv = (e1>e0) ? 1.f/(float)(e1-e0) : 0.f;
    A2[(size_t)i*1280 + 256 + r*256 + f] = f2bf(s*inv);
}

// ---------------- MFMA GEMM: C[M x Nout] = act(A[M x K] * Bt[Nout x K]^T + bias) ----------------
__global__ __launch_bounds__(256) void gemm_bt(const __hip_bfloat16* __restrict__ A, int lda,
                                               const __hip_bfloat16* __restrict__ Bt,
                                               const float* __restrict__ bias,
                                               __hip_bfloat16* __restrict__ C, int ldc,
                                               int M, int K, int relu)
{
    __shared__ __align__(16) __hip_bfloat16 lds_a[128*32];
    __shared__ __align__(16) __hip_bfloat16 lds_b[128*32];
    const int tid    = threadIdx.x;
    const int tile_m = blockIdx.x * 128;
    const int tile_n = blockIdx.y * 128;
    const int wave   = tid >> 6;
    const int lane   = tid & 63;
    const int wm = wave >> 1, wn = wave & 1;     // 2x2 wave grid: 64x64 each
    const int fm = lane & 15;                    // frag m (A) / n (Bt) / col (C)
    const int q  = lane >> 4;                    // 0..3

    floatx4 acc[4][4];
    #pragma unroll
    for (int i=0;i<4;i++)
        #pragma unroll
        for (int j=0;j<4;j++) acc[i][j] = (floatx4){0.f,0.f,0.f,0.f};

    const int srow   = tid >> 2;                 // 0..63 (plus 64 per pass)
    const int schunk = (tid & 3) * 8;            // element offset along K

    for (int k0 = 0; k0 < K; k0 += 32) {
        __syncthreads();
        #pragma unroll
        for (int p=0;p<2;p++) {
            int row = p*64 + srow;
            int ga  = min(tile_m + row, M-1);    // clamp: pad rows read row M-1 (discarded)
            uint4 v = *(const uint4*)(A + (size_t)ga*lda + k0 + schunk);
            *(uint4*)(&lds_a[row*32 + schunk]) = v;
        }
        #pragma unroll
        for (int p=0;p<2;p++) {
            int row = p*64 + srow;
            uint4 v = *(const uint4*)(Bt + (size_t)(tile_n + row)*K + k0 + schunk);
            *(uint4*)(&lds_b[row*32 + schunk]) = v;
        }
        __syncthreads();

        short8 afr[4], bfr[4];
        #pragma unroll
        for (int i=0;i<4;i++) {
            afr[i] = *(const short8*)(&lds_a[(wm*64 + i*16 + fm)*32 + q*8]);
            bfr[i] = *(const short8*)(&lds_b[(wn*64 + i*16 + fm)*32 + q*8]);
        }
        #pragma unroll
        for (int i=0;i<4;i++)
            #pragma unroll
            for (int j=0;j<4;j++)
                acc[i][j] = __builtin_amdgcn_mfma_f32_16x16x32_bf16(afr[i], bfr[j], acc[i][j], 0,0,0);
    }

    const int crow_base = tile_m + wm*64;
    const int ccol_base = tile_n + wn*64;
    #pragma unroll
    for (int i=0;i<4;i++) {
        #pragma unroll
        for (int j=0;j<4;j++) {
            int c  = ccol_base + j*16 + fm;
            float bb = bias[c];
            #pragma unroll
            for (int rg=0; rg<4; rg++) {
                int r = crow_base + i*16 + q*4 + rg;
                if (r < M) {
                    float v = acc[i][j][rg] + bb;
                    if (relu) v = fmaxf(v, 0.f);
                    C[(size_t)r*ldc + c] = f2bf(v);
                }
            }
        }
    }
}

// ---------------- attention scores (CSR-position-parallel, one wave per position) ----------------
// score layout: [HEADS][E] planes, indexed by CSR POSITION (matches attn_agg reads).
__global__ __launch_bounds__(256) void score_kernel(const __hip_bfloat16* __restrict__ qkvs,
                                                    const int* __restrict__ csr_src,
                                                    const int* __restrict__ csr_dst,
                                                    float* __restrict__ score)
{
    int p = blockIdx.x*4 + (threadIdx.x >> 6);
    if (p >= E_EDGES) return;
    int lane = threadIdx.x & 63;
    int src = csr_src[p], dst = csr_dst[p];
    // lane covers dims 4*lane .. 4*lane+3 of the 256-dim q/k rows; head = lane/16
    const ushort4 qv = *(const ushort4*)(qkvs + (size_t)dst*1024 + lane*4);
    const ushort4 kv = *(const ushort4*)(qkvs + (size_t)src*1024 + 256 + lane*4);
    float d = bfbits2f(qv.x)*bfbits2f(kv.x) + bfbits2f(qv.y)*bfbits2f(kv.y)
            + bfbits2f(qv.z)*bfbits2f(kv.z) + bfbits2f(qv.w)*bfbits2f(kv.w);
    #pragma unroll
    for (int o=1;o<16;o<<=1) d += __shfl_xor(d, o, 64);
    if ((lane & 15) == 0)
        score[(size_t)(lane >> 4)*E_EDGES + p] = d * 0.125f;   // 1/sqrt(64)
}

// ---------------- attention aggregate (one wave per (node, head)) ----------------
__global__ __launch_bounds__(256) void attn_agg_kernel(const __hip_bfloat16* __restrict__ qkvs,
                                                       const float* __restrict__ score,
                                                       const int* __restrict__ row_ptr,
                                                       const int* __restrict__ csr_src,
                                                       __hip_bfloat16* __restrict__ hatt)
{
    int i = blockIdx.x;
    int h = threadIdx.x >> 6;
    int l = threadIdx.x & 63;
    int e0 = row_ptr[i*R_REL], e1 = row_ptr[i*R_REL + R_REL];
    int deg = e1 - e0;
    const float* sp = score + (size_t)h*E_EDGES;

    // pass 1: max over this node's scores (lanes = edges)
    float m = -1e30f;
    for (int b = 0; b < deg; b += 64) {
        int j = b + l;
        float sc = (j < deg) ? sp[e0 + j] : -1e30f;
        m = fmaxf(m, sc);
    }
    #pragma unroll
    for (int o=32;o>0;o>>=1) m = fmaxf(m, __shfl_xor(m, o, 64));

    // pass 2: denom
    float ssum = 0.f;
    for (int b = 0; b < deg; b += 64) {
        int j = b + l;
        if (j < deg) ssum += __expf(sp[e0 + j] - m);
    }
    #pragma unroll
    for (int o=32;o>0;o>>=1) ssum += __shfl_xor(ssum, o, 64);
    float inv = 1.f / fmaxf(ssum, 1e-16f);

    // pass 3: weighted V gather; per-lane weight for edge (b+l), broadcast via shfl
    float acc = 0.f;
    for (int b = 0; b < deg; b += 64) {
        int j = b + l;
        float w = (j < deg) ? __expf(sp[e0 + j] - m) * inv : 0.f;
        int nchunk = min(64, deg - b);
        #pragma unroll 4
        for (int t = 0; t < nchunk; t++) {
            float alpha = __shfl(w, t, 64);
            int s = csr_src[e0 + b + t];
            float vl = bf2f(qkvs[(size_t)s*1024 + 512 + h*64 + l]);
            acc += alpha * vl;
        }
    }
    float skip = bf2f(qkvs[(size_t)i*1024 + 768 + h*64 + l]);
    hatt[(size_t)i*256 + h*64 + l] = f2bf(acc + skip);
}

// ---------------- GRU elementwise (bf16 gates, fp32 math, fp32 out) ----------------
__global__ void gru_kernel(const __hip_bfloat16* __restrict__ gi,
                           const __hip_bfloat16* __restrict__ gh,
                           const float* __restrict__ hprev,
                           float* __restrict__ out)
{
    int idx = blockIdx.x*256 + threadIdx.x;
    if (idx >= N_NODES*HIDF) return;
    int i = idx / HIDF, c = idx % HIDF;
    size_t gb = (size_t)i*768;
    float ir = bf2f(gi[gb + c]), iz = bf2f(gi[gb + 256 + c]), in = bf2f(gi[gb + 512 + c]);
    float hr = bf2f(gh[gb + c]), hz = bf2f(gh[gb + 256 + c]), hn = bf2f(gh[gb + 512 + c]);
    float r = 1.f/(1.f + __expf(-(ir+hr)));
    float z = 1.f/(1.f + __expf(-(iz+hz)));
    float n = tanhf(in + r*hn);
    float h = hprev[idx];
    out[idx] = (1.f - z)*n + z*h;
}

// ---------------- launch ----------------
// Inputs fp32 (verified round 3); bf16 internally for MFMA. Workspace ~102 MB:
//   P1 (30.72 MB): A1 -> h2 -> hatt -> gh
//   P2 (51.2  MB): A2 -> qkvs -> gi
// Ordering: gemm4 (reads hatt, writes gi) BEFORE gemm5 (writes gh over hatt).
extern "C" void kernel_launch(void* const* d_in, const int* in_sizes, int n_in,
                              void* d_out, int out_size, void* d_ws, size_t ws_size,
                              hipStream_t stream)
{
    const float* x       = (const float*)d_in[0];
    const int* edge_index= (const int*)d_in[1];
    const int* edge_type = (const int*)d_in[2];
    const float* hprev   = (const float*)d_in[3];
    const float* W1      = (const float*)d_in[4];
    const float* root1   = (const float*)d_in[5];
    const float* b1      = (const float*)d_in[6];
    const float* W2      = (const float*)d_in[7];
    const float* root2   = (const float*)d_in[8];
    const float* b2      = (const float*)d_in[9];
    const float* Wq      = (const float*)d_in[10];
    const float* bq      = (const float*)d_in[11];
    const float* Wk      = (const float*)d_in[12];
    const float* bk      = (const float*)d_in[13];
    const float* Wv      = (const float*)d_in[14];
    const float* bv      = (const float*)d_in[15];
    const float* Wskip   = (const float*)d_in[16];
    const float* bskip   = (const float*)d_in[17];
    const float* W_ih    = (const float*)d_in[18];
    const float* b_ih    = (const float*)d_in[19];
    const float* W_hh    = (const float*)d_in[20];
    const float* b_hh    = (const float*)d_in[21];

    char* ws = (char*)d_ws;
    size_t off = 0;
    auto take = [&](size_t bytes)->char* {
        char* p = ws + off;
        off = (off + bytes + 255) & ~(size_t)255;
        return p;
    };
    int* cnt        = (int*)take((size_t)NRKEYS*4);
    int* row_ptr    = (int*)take((size_t)(NRKEYS+1)*4);
    int* cursor     = (int*)take((size_t)NRKEYS*4);
    int* csr_src    = (int*)take((size_t)E_EDGES*4);
    int* csr_dst    = (int*)take((size_t)E_EDGES*4);
    int* blocksum   = (int*)take((size_t)SCAN_BLOCKS*4);
    int* blockoff   = (int*)take((size_t)(SCAN_BLOCKS+1)*4);
    float* score    = (float*)take((size_t)R_REL*E_EDGES*4);   // [HEADS][E], CSR-position-indexed
    __hip_bfloat16* B1t   = (__hip_bfloat16*)take((size_t)256*640*2);
    __hip_bfloat16* B2t   = (__hip_bfloat16*)take((size_t)256*1280*2);
    __hip_bfloat16* B3t   = (__hip_bfloat16*)take((size_t)1024*256*2);
    __hip_bfloat16* Biht  = (__hip_bfloat16*)take((size_t)768*256*2);
    __hip_bfloat16* Bhht  = (__hip_bfloat16*)take((size_t)768*256*2);
    float*          bias3 = (float*)take((size_t)1024*4);
    __hip_bfloat16* hprev_bf = (__hip_bfloat16*)take((size_t)N_NODES*256*2);
    // P1: max(A1 N*640, h2 N*256, hatt N*256, gh N*768) bf16
    char* P1 = take((size_t)N_NODES*768*2);
    // P2: max(A2 N*1280, qkvs N*1024, gi N*768) bf16
    char* P2 = take((size_t)N_NODES*1280*2);

    __hip_bfloat16* A1   = (__hip_bfloat16*)P1;   // [N,640]  dead after gemm1
    __hip_bfloat16* h2   = (__hip_bfloat16*)P1;   // [N,256]  dead after gemm3
    __hip_bfloat16* hatt = (__hip_bfloat16*)P1;   // [N,256]  dead after gemm4
    __hip_bfloat16* gh   = (__hip_bfloat16*)P1;   // [N,768]  written gemm5
    __hip_bfloat16* A2   = (__hip_bfloat16*)P2;   // [N,1280] dead after gemm2
    __hip_bfloat16* qkvs = (__hip_bfloat16*)P2;   // [N,1024] dead after attn_agg
    __hip_bfloat16* gi   = (__hip_bfloat16*)P2;   // [N,768]  written gemm4

    hipMemsetAsync(cnt, 0, (size_t)NRKEYS*4, stream);
    count_kernel<<<(E_EDGES+255)/256, 256, 0, stream>>>(edge_index, edge_type, cnt);
    scan_reduce_kernel<<<SCAN_BLOCKS, 1024, 0, stream>>>(cnt, blocksum);
    scan_sums_kernel<<<1, 128, 0, stream>>>(blocksum, blockoff);
    scan_apply_kernel<<<SCAN_BLOCKS, 1024, 0, stream>>>(cnt, blockoff, row_ptr, cursor);
    fill_kernel<<<(E_EDGES+255)/256, 256, 0, stream>>>(edge_index, edge_type, cursor, csr_src, csr_dst);

    make_b1t<<<(256*640+255)/256, 256, 0, stream>>>(root1, W1, B1t);
    make_b2t<<<(256*1280+255)/256, 256, 0, stream>>>(root2, W2, B2t);
    make_b3t<<<(1024*256+255)/256, 256, 0, stream>>>(Wq, Wk, Wv, Wskip, bq, bk, bv, bskip, B3t, bias3);
    cvt_f32_bf16<<<(768*256+255)/256, 256, 0, stream>>>(W_ih, Biht, 768*256);
    cvt_f32_bf16<<<(768*256+255)/256, 256, 0, stream>>>(W_hh, Bhht, 768*256);
    cvt_f32_bf16<<<(N_NODES*256+255)/256, 256, 0, stream>>>(hprev, hprev_bf, N_NODES*256);

    agg1_kernel<<<NRKEYS, 128, 0, stream>>>(x, row_ptr, csr_src, A1);

    dim3 g12(157, 2);
    // h1 = relu(A1 * B1) written into A2 cols 0..255 (ldc=1280)
    gemm_bt<<<g12, 256, 0, stream>>>(A1, 640, B1t, b1, A2, 1280, N_NODES, 640, 1);

    agg2_kernel<<<NRKEYS, 256, 0, stream>>>(row_ptr, csr_src, A2);

    // h2 overwrites A1 (dead) in P1
    gemm_bt<<<g12, 256, 0, stream>>>(A2, 1280, B2t, b2, h2, 256, N_NODES, 1280, 1);

    // qkvs overwrites A2 (dead) in P2
    dim3 g3(157, 8);
    gemm_bt<<<g3, 256, 0, stream>>>(h2, 256, B3t, bias3, qkvs, 1024, N_NODES, 256, 0);

    // attention: CSR-position-parallel scores, then per-(node,head) aggregate
    score_kernel<<<E_EDGES/4, 256, 0, stream>>>(qkvs, csr_src, csr_dst, score);
    attn_agg_kernel<<<N_NODES, 256, 0, stream>>>(qkvs, score, row_ptr, csr_src, hatt);

    dim3 g45(157, 6);
    // gi overwrites qkvs (dead) in P2 -- must run before gemm5
    gemm_bt<<<g45, 256, 0, stream>>>(hatt,     256, Biht, b_ih, gi, 768, N_NODES, 256, 0);
    // gh overwrites hatt (dead) in P1
    gemm_bt<<<g45, 256, 0, stream>>>(hprev_bf, 256, Bhht, b_hh, gh, 768, N_NODES, 256, 0);

    gru_kernel<<<(N_NODES*HIDF+255)/256, 256, 0, stream>>>(gi, gh, hprev, (float*)d_out);
}

// Round 7
// 553.525 us; speedup vs baseline: 1.1366x; 1.1366x over previous
//
#include <hip/hip_runtime.h>
#include <hip/hip_bf16.h>
#include <stdint.h>

#define N_NODES 20000
#define E_EDGES 320000
#define IN_F    128
#define HIDF    256
#define R_REL   4
#define NRKEYS  (N_NODES*R_REL)   // 80000
#define SCAN_BLOCKS 80            // 80*1024 = 81920 >= NRKEYS

typedef __attribute__((ext_vector_type(8))) short  short8;
typedef __attribute__((ext_vector_type(4))) float  floatx4;

__device__ __forceinline__ float bf2f(__hip_bfloat16 v){ return __bfloat162float(v); }
__device__ __forceinline__ __hip_bfloat16 f2bf(float v){ return __float2bfloat16(v); }
__device__ __forceinline__ float bfbits2f(unsigned short u){ return __uint_as_float(((unsigned)u)<<16); }
__device__ __forceinline__ unsigned short f2bfbits(float v){
    __hip_bfloat16 h = __float2bfloat16(v);
    return *(unsigned short*)&h;
}
__device__ __forceinline__ unsigned pack_bf2(float a, float b){
    return (unsigned)f2bfbits(a) | ((unsigned)f2bfbits(b) << 16);
}

// ---------------- CSR build ----------------
__global__ void count_kernel(const int* __restrict__ ei, const int* __restrict__ et,
                             int* __restrict__ cnt)
{
    int e = blockIdx.x*256 + threadIdx.x;
    if (e >= E_EDGES) return;
    int dst = ei[E_EDGES + e];
    atomicAdd(&cnt[dst*R_REL + et[e]], 1);
}

// 3-phase parallel exclusive scan over cnt[NRKEYS] -> row_ptr, cursor
__global__ __launch_bounds__(1024) void scan_reduce_kernel(const int* __restrict__ cnt,
                                                           int* __restrict__ blocksum)
{
    int ix = blockIdx.x*1024 + threadIdx.x;
    int v = (ix < NRKEYS) ? cnt[ix] : 0;
    #pragma unroll
    for (int o=32;o>0;o>>=1) v += __shfl_xor(v, o, 64);
    __shared__ int wsum[16];
    int wave = threadIdx.x >> 6, lane = threadIdx.x & 63;
    if (lane == 0) wsum[wave] = v;
    __syncthreads();
    if (threadIdx.x == 0) {
        int s = 0;
        #pragma unroll
        for (int w=0;w<16;w++) s += wsum[w];
        blocksum[blockIdx.x] = s;
    }
}

__global__ __launch_bounds__(128) void scan_sums_kernel(const int* __restrict__ blocksum,
                                                        int* __restrict__ blockoff)
{
    __shared__ int s[128];
    int t = threadIdx.x;
    int v = (t < SCAN_BLOCKS) ? blocksum[t] : 0;
    s[t] = v; __syncthreads();
    for (int off=1; off<128; off<<=1) {
        int u = (t>=off) ? s[t-off] : 0;
        __syncthreads();
        s[t] += u;
        __syncthreads();
    }
    if (t < SCAN_BLOCKS) blockoff[t] = s[t] - v;   // exclusive
}

__global__ __launch_bounds__(1024) void scan_apply_kernel(const int* __restrict__ cnt,
                                                          const int* __restrict__ blockoff,
                                                          int* __restrict__ row_ptr,
                                                          int* __restrict__ cursor)
{
    __shared__ int s[1024];
    int t = threadIdx.x;
    int ix = blockIdx.x*1024 + t;
    int v = (ix < NRKEYS) ? cnt[ix] : 0;
    s[t] = v; __syncthreads();
    for (int off=1; off<1024; off<<=1) {
        int u = (t>=off) ? s[t-off] : 0;
        __syncthreads();
        s[t] += u;
        __syncthreads();
    }
    if (ix < NRKEYS) {
        int excl = blockoff[blockIdx.x] + s[t] - v;
        row_ptr[ix] = excl;
        cursor[ix]  = excl;
        if (ix == NRKEYS-1) row_ptr[NRKEYS] = excl + v;
    }
}

// records BOTH endpoints per CSR position (position-indexed downstream)
__global__ void fill_kernel(const int* __restrict__ ei, const int* __restrict__ et,
                            int* __restrict__ cursor,
                            int* __restrict__ csr_src, int* __restrict__ csr_dst)
{
    int e = blockIdx.x*256 + threadIdx.x;
    if (e >= E_EDGES) return;
    int src = ei[e];
    int dst = ei[E_EDGES + e];
    int key = dst*R_REL + et[e];
    int pos = atomicAdd(&cursor[key], 1);
    csr_src[pos] = src;
    csr_dst[pos] = dst;
}

// ---------------- weight prep: fp32 sources -> bf16 B^T = [Nout][K] ----------------
__global__ void make_b1t(const float* __restrict__ root1,
                         const float* __restrict__ W1,
                         __hip_bfloat16* __restrict__ B1t)
{
    int idx = blockIdx.x*256 + threadIdx.x;         // n*640 + k
    if (idx >= 256*640) return;
    int n = idx / 640, k = idx % 640;
    float v;
    if (k < 128) v = root1[k*256 + n];
    else         v = W1[(k-128)*256 + n];           // W1 contiguous [R*128][256]
    B1t[idx] = f2bf(v);
}

__global__ void make_b2t(const float* __restrict__ root2,
                         const float* __restrict__ W2,
                         __hip_bfloat16* __restrict__ B2t)
{
    int idx = blockIdx.x*256 + threadIdx.x;         // n*1280 + k
    if (idx >= 256*1280) return;
    int n = idx / 1280, k = idx % 1280;
    float v;
    if (k < 256) v = root2[k*256 + n];
    else         v = W2[(k-256)*256 + n];           // W2 contiguous [R*256][256]
    B2t[idx] = f2bf(v);
}

__global__ void make_b3t(const float* __restrict__ Wq, const float* __restrict__ Wk,
                         const float* __restrict__ Wv, const float* __restrict__ Wsk,
                         const float* __restrict__ bq, const float* __restrict__ bk,
                         const float* __restrict__ bv, const float* __restrict__ bsk,
                         __hip_bfloat16* __restrict__ B3t, float* __restrict__ bias3)
{
    int idx = blockIdx.x*256 + threadIdx.x;         // n*256 + k, n<1024
    if (idx >= 1024*256) return;
    int n = idx / 256, k = idx % 256;
    int g = n >> 8, nn = n & 255;
    const float* W = (g==0)?Wq:(g==1)?Wk:(g==2)?Wv:Wsk;
    B3t[idx] = f2bf(W[k*256 + nn]);
    if (k == 0) {
        const float* B = (g==0)?bq:(g==1)?bk:(g==2)?bv:bsk;
        bias3[n] = B[nn];
    }
}

// generic fp32 -> bf16 elementwise convert (layout-preserving)
__global__ void cvt_f32_bf16(const float* __restrict__ in, __hip_bfloat16* __restrict__ out, int n)
{
    int i = blockIdx.x*256 + threadIdx.x;
    if (i < n) out[i] = f2bf(in[i]);
}

// ---------------- RGCN aggregation: one WAVE per (node,rel) key, unroll-4 ILP ----------------
// agg1: x fp32 [N,128]; lane covers dims 2*lane..2*lane+1 (float2, 8 B)
__global__ __launch_bounds__(256) void agg1_kernel(const float* __restrict__ x,
                                                   const int* __restrict__ row_ptr,
                                                   const int* __restrict__ csr_src,
                                                   __hip_bfloat16* __restrict__ A1)
{
    int b = blockIdx.x*4 + (threadIdx.x >> 6);   // key = i*4 + r
    int lane = threadIdx.x & 63;
    int i = b >> 2, r = b & 3;
    int e0 = row_ptr[b], e1 = row_ptr[b+1];
    float sx0=0.f,sy0=0.f, sx1=0.f,sy1=0.f, sx2=0.f,sy2=0.f, sx3=0.f,sy3=0.f;
    int e = e0;
    for (; e+4 <= e1; e += 4) {
        int i0=csr_src[e], i1=csr_src[e+1], i2=csr_src[e+2], i3=csr_src[e+3];
        float2 v0 = *(const float2*)(x + (size_t)i0*IN_F + lane*2);
        float2 v1 = *(const float2*)(x + (size_t)i1*IN_F + lane*2);
        float2 v2 = *(const float2*)(x + (size_t)i2*IN_F + lane*2);
        float2 v3 = *(const float2*)(x + (size_t)i3*IN_F + lane*2);
        sx0+=v0.x; sy0+=v0.y; sx1+=v1.x; sy1+=v1.y;
        sx2+=v2.x; sy2+=v2.y; sx3+=v3.x; sy3+=v3.y;
    }
    for (; e < e1; e++) {
        int i0 = csr_src[e];
        float2 v = *(const float2*)(x + (size_t)i0*IN_F + lane*2);
        sx0+=v.x; sy0+=v.y;
    }
    float sx = (sx0+sx1)+(sx2+sx3);
    float sy = (sy0+sy1)+(sy2+sy3);
    float inv = (e1>e0) ? 1.f/(float)(e1-e0) : 0.f;
    *(unsigned*)(A1 + (size_t)i*640 + 128 + r*128 + lane*2) = pack_bf2(sx*inv, sy*inv);
    if (r == 0) {
        float2 v = *(const float2*)(x + (size_t)i*IN_F + lane*2);
        *(unsigned*)(A1 + (size_t)i*640 + lane*2) = pack_bf2(v.x, v.y);
    }
}

// agg2: h1 bf16 in A2 cols 0..255 (ld 1280); lane covers dims 4*lane..4*lane+3 (ushort4, 8 B)
__global__ __launch_bounds__(256) void agg2_kernel(const int* __restrict__ row_ptr,
                                                   const int* __restrict__ csr_src,
                                                   __hip_bfloat16* __restrict__ A2)
{
    int b = blockIdx.x*4 + (threadIdx.x >> 6);
    int lane = threadIdx.x & 63;
    int i = b >> 2, r = b & 3;
    int e0 = row_ptr[b], e1 = row_ptr[b+1];
    float a0=0.f,a1=0.f,a2=0.f,a3=0.f;   // slot 0 dims
    float b0=0.f,b1=0.f,b2=0.f,b3=0.f;   // slot 1
    float c0=0.f,c1=0.f,c2=0.f,c3=0.f;   // slot 2
    float d0=0.f,d1=0.f,d2=0.f,d3=0.f;   // slot 3
    int e = e0;
    for (; e+4 <= e1; e += 4) {
        int i0=csr_src[e], i1=csr_src[e+1], i2=csr_src[e+2], i3=csr_src[e+3];
        ushort4 u0 = *(const ushort4*)(A2 + (size_t)i0*1280 + lane*4);
        ushort4 u1 = *(const ushort4*)(A2 + (size_t)i1*1280 + lane*4);
        ushort4 u2 = *(const ushort4*)(A2 + (size_t)i2*1280 + lane*4);
        ushort4 u3 = *(const ushort4*)(A2 + (size_t)i3*1280 + lane*4);
        a0+=bfbits2f(u0.x); a1+=bfbits2f(u0.y); a2+=bfbits2f(u0.z); a3+=bfbits2f(u0.w);
        b0+=bfbits2f(u1.x); b1+=bfbits2f(u1.y); b2+=bfbits2f(u1.z); b3+=bfbits2f(u1.w);
        c0+=bfbits2f(u2.x); c1+=bfbits2f(u2.y); c2+=bfbits2f(u2.z); c3+=bfbits2f(u2.w);
        d0+=bfbits2f(u3.x); d1+=bfbits2f(u3.y); d2+=bfbits2f(u3.z); d3+=bfbits2f(u3.w);
    }
    for (; e < e1; e++) {
        int i0 = csr_src[e];
        ushort4 u = *(const ushort4*)(A2 + (size_t)i0*1280 + lane*4);
        a0+=bfbits2f(u.x); a1+=bfbits2f(u.y); a2+=bfbits2f(u.z); a3+=bfbits2f(u.w);
    }
    float s0=(a0+b0)+(c0+d0), s1=(a1+b1)+(c1+d1), s2=(a2+b2)+(c2+d2), s3=(a3+b3)+(c3+d3);
    float inv = (e1>e0) ? 1.f/(float)(e1-e0) : 0.f;
    uint2 w;
    w.x = pack_bf2(s0*inv, s1*inv);
    w.y = pack_bf2(s2*inv, s3*inv);
    *(uint2*)(A2 + (size_t)i*1280 + 256 + r*256 + lane*4) = w;
}

// ---------------- MFMA GEMM: C[M x Nout] = act(A[M x K] * Bt[Nout x K]^T + bias) ----------------
__global__ __launch_bounds__(256) void gemm_bt(const __hip_bfloat16* __restrict__ A, int lda,
                                               const __hip_bfloat16* __restrict__ Bt,
                                               const float* __restrict__ bias,
                                               __hip_bfloat16* __restrict__ C, int ldc,
                                               int M, int K, int relu)
{
    __shared__ __align__(16) __hip_bfloat16 lds_a[128*32];
    __shared__ __align__(16) __hip_bfloat16 lds_b[128*32];
    const int tid    = threadIdx.x;
    const int tile_m = blockIdx.x * 128;
    const int tile_n = blockIdx.y * 128;
    const int wave   = tid >> 6;
    const int lane   = tid & 63;
    const int wm = wave >> 1, wn = wave & 1;     // 2x2 wave grid: 64x64 each
    const int fm = lane & 15;                    // frag m (A) / n (Bt) / col (C)
    const int q  = lane >> 4;                    // 0..3

    floatx4 acc[4][4];
    #pragma unroll
    for (int i=0;i<4;i++)
        #pragma unroll
        for (int j=0;j<4;j++) acc[i][j] = (floatx4){0.f,0.f,0.f,0.f};

    const int srow   = tid >> 2;                 // 0..63 (plus 64 per pass)
    const int schunk = (tid & 3) * 8;            // element offset along K

    for (int k0 = 0; k0 < K; k0 += 32) {
        __syncthreads();
        #pragma unroll
        for (int p=0;p<2;p++) {
            int row = p*64 + srow;
            int ga  = min(tile_m + row, M-1);    // clamp: pad rows read row M-1 (discarded)
            uint4 v = *(const uint4*)(A + (size_t)ga*lda + k0 + schunk);
            *(uint4*)(&lds_a[row*32 + schunk]) = v;
        }
        #pragma unroll
        for (int p=0;p<2;p++) {
            int row = p*64 + srow;
            uint4 v = *(const uint4*)(Bt + (size_t)(tile_n + row)*K + k0 + schunk);
            *(uint4*)(&lds_b[row*32 + schunk]) = v;
        }
        __syncthreads();

        short8 afr[4], bfr[4];
        #pragma unroll
        for (int i=0;i<4;i++) {
            afr[i] = *(const short8*)(&lds_a[(wm*64 + i*16 + fm)*32 + q*8]);
            bfr[i] = *(const short8*)(&lds_b[(wn*64 + i*16 + fm)*32 + q*8]);
        }
        #pragma unroll
        for (int i=0;i<4;i++)
            #pragma unroll
            for (int j=0;j<4;j++)
                acc[i][j] = __builtin_amdgcn_mfma_f32_16x16x32_bf16(afr[i], bfr[j], acc[i][j], 0,0,0);
    }

    const int crow_base = tile_m + wm*64;
    const int ccol_base = tile_n + wn*64;
    #pragma unroll
    for (int i=0;i<4;i++) {
        #pragma unroll
        for (int j=0;j<4;j++) {
            int c  = ccol_base + j*16 + fm;
            float bb = bias[c];
            #pragma unroll
            for (int rg=0; rg<4; rg++) {
                int r = crow_base + i*16 + q*4 + rg;
                if (r < M) {
                    float v = acc[i][j][rg] + bb;
                    if (relu) v = fmaxf(v, 0.f);
                    C[(size_t)r*ldc + c] = f2bf(v);
                }
            }
        }
    }
}

// ---------------- attention scores (CSR-position-parallel, one wave per position) ----------------
// score layout: [HEADS][E] planes, indexed by CSR POSITION (matches attn_agg reads).
__global__ __launch_bounds__(256) void score_kernel(const __hip_bfloat16* __restrict__ qkvs,
                                                    const int* __restrict__ csr_src,
                                                    const int* __restrict__ csr_dst,
                                                    float* __restrict__ score)
{
    int p = blockIdx.x*4 + (threadIdx.x >> 6);
    if (p >= E_EDGES) return;
    int lane = threadIdx.x & 63;
    int src = csr_src[p], dst = csr_dst[p];
    // lane covers dims 4*lane .. 4*lane+3 of the 256-dim q/k rows; head = lane/16
    const ushort4 qv = *(const ushort4*)(qkvs + (size_t)dst*1024 + lane*4);
    const ushort4 kv = *(const ushort4*)(qkvs + (size_t)src*1024 + 256 + lane*4);
    float d = bfbits2f(qv.x)*bfbits2f(kv.x) + bfbits2f(qv.y)*bfbits2f(kv.y)
            + bfbits2f(qv.z)*bfbits2f(kv.z) + bfbits2f(qv.w)*bfbits2f(kv.w);
    #pragma unroll
    for (int o=1;o<16;o<<=1) d += __shfl_xor(d, o, 64);
    if ((lane & 15) == 0)
        score[(size_t)(lane >> 4)*E_EDGES + p] = d * 0.125f;   // 1/sqrt(64)
}

// ---------------- attention aggregate (one wave per (node, head)) ----------------
__global__ __launch_bounds__(256) void attn_agg_kernel(const __hip_bfloat16* __restrict__ qkvs,
                                                       const float* __restrict__ score,
                                                       const int* __restrict__ row_ptr,
                                                       const int* __restrict__ csr_src,
                                                       __hip_bfloat16* __restrict__ hatt)
{
    int i = blockIdx.x;
    int h = threadIdx.x >> 6;
    int l = threadIdx.x & 63;
    int e0 = row_ptr[i*R_REL], e1 = row_ptr[i*R_REL + R_REL];
    int deg = e1 - e0;
    const float* sp = score + (size_t)h*E_EDGES;

    // pass 1: max over this node's scores (lanes = edges)
    float m = -1e30f;
    for (int b = 0; b < deg; b += 64) {
        int j = b + l;
        float sc = (j < deg) ? sp[e0 + j] : -1e30f;
        m = fmaxf(m, sc);
    }
    #pragma unroll
    for (int o=32;o>0;o>>=1) m = fmaxf(m, __shfl_xor(m, o, 64));

    // pass 2: denom
    float ssum = 0.f;
    for (int b = 0; b < deg; b += 64) {
        int j = b + l;
        if (j < deg) ssum += __expf(sp[e0 + j] - m);
    }
    #pragma unroll
    for (int o=32;o>0;o>>=1) ssum += __shfl_xor(ssum, o, 64);
    float inv = 1.f / fmaxf(ssum, 1e-16f);

    // pass 3: weighted V gather; per-lane weight for edge (b+l), broadcast via shfl
    float acc = 0.f;
    for (int b = 0; b < deg; b += 64) {
        int j = b + l;
        float w = (j < deg) ? __expf(sp[e0 + j] - m) * inv : 0.f;
        int nchunk = min(64, deg - b);
        #pragma unroll 4
        for (int t = 0; t < nchunk; t++) {
            float alpha = __shfl(w, t, 64);
            int s = csr_src[e0 + b + t];
            float vl = bf2f(qkvs[(size_t)s*1024 + 512 + h*64 + l]);
            acc += alpha * vl;
        }
    }
    float skip = bf2f(qkvs[(size_t)i*1024 + 768 + h*64 + l]);
    hatt[(size_t)i*256 + h*64 + l] = f2bf(acc + skip);
}

// ---------------- GRU elementwise (bf16 gates, fp32 math, fp32 out) ----------------
__global__ void gru_kernel(const __hip_bfloat16* __restrict__ gi,
                           const __hip_bfloat16* __restrict__ gh,
                           const float* __restrict__ hprev,
                           float* __restrict__ out)
{
    int idx = blockIdx.x*256 + threadIdx.x;
    if (idx >= N_NODES*HIDF) return;
    int i = idx / HIDF, c = idx % HIDF;
    size_t gb = (size_t)i*768;
    float ir = bf2f(gi[gb + c]), iz = bf2f(gi[gb + 256 + c]), in = bf2f(gi[gb + 512 + c]);
    float hr = bf2f(gh[gb + c]), hz = bf2f(gh[gb + 256 + c]), hn = bf2f(gh[gb + 512 + c]);
    float r = 1.f/(1.f + __expf(-(ir+hr)));
    float z = 1.f/(1.f + __expf(-(iz+hz)));
    float n = tanhf(in + r*hn);
    float h = hprev[idx];
    out[idx] = (1.f - z)*n + z*h;
}

// ---------------- launch ----------------
// Inputs fp32 (verified round 3); bf16 internally for MFMA. Workspace ~102 MB:
//   P1 (30.72 MB): A1 -> h2 -> hatt -> gh
//   P2 (51.2  MB): A2 -> qkvs -> gi
// Ordering: gemm4 (reads hatt, writes gi) BEFORE gemm5 (writes gh over hatt).
extern "C" void kernel_launch(void* const* d_in, const int* in_sizes, int n_in,
                              void* d_out, int out_size, void* d_ws, size_t ws_size,
                              hipStream_t stream)
{
    const float* x       = (const float*)d_in[0];
    const int* edge_index= (const int*)d_in[1];
    const int* edge_type = (const int*)d_in[2];
    const float* hprev   = (const float*)d_in[3];
    const float* W1      = (const float*)d_in[4];
    const float* root1   = (const float*)d_in[5];
    const float* b1      = (const float*)d_in[6];
    const float* W2      = (const float*)d_in[7];
    const float* root2   = (const float*)d_in[8];
    const float* b2      = (const float*)d_in[9];
    const float* Wq      = (const float*)d_in[10];
    const float* bq      = (const float*)d_in[11];
    const float* Wk      = (const float*)d_in[12];
    const float* bk      = (const float*)d_in[13];
    const float* Wv      = (const float*)d_in[14];
    const float* bv      = (const float*)d_in[15];
    const float* Wskip   = (const float*)d_in[16];
    const float* bskip   = (const float*)d_in[17];
    const float* W_ih    = (const float*)d_in[18];
    const float* b_ih    = (const float*)d_in[19];
    const float* W_hh    = (const float*)d_in[20];
    const float* b_hh    = (const float*)d_in[21];

    char* ws = (char*)d_ws;
    size_t off = 0;
    auto take = [&](size_t bytes)->char* {
        char* p = ws + off;
        off = (off + bytes + 255) & ~(size_t)255;
        return p;
    };
    int* cnt        = (int*)take((size_t)NRKEYS*4);
    int* row_ptr    = (int*)take((size_t)(NRKEYS+1)*4);
    int* cursor     = (int*)take((size_t)NRKEYS*4);
    int* csr_src    = (int*)take((size_t)E_EDGES*4);
    int* csr_dst    = (int*)take((size_t)E_EDGES*4);
    int* blocksum   = (int*)take((size_t)SCAN_BLOCKS*4);
    int* blockoff   = (int*)take((size_t)(SCAN_BLOCKS+1)*4);
    float* score    = (float*)take((size_t)R_REL*E_EDGES*4);   // [HEADS][E], CSR-position-indexed
    __hip_bfloat16* B1t   = (__hip_bfloat16*)take((size_t)256*640*2);
    __hip_bfloat16* B2t   = (__hip_bfloat16*)take((size_t)256*1280*2);
    __hip_bfloat16* B3t   = (__hip_bfloat16*)take((size_t)1024*256*2);
    __hip_bfloat16* Biht  = (__hip_bfloat16*)take((size_t)768*256*2);
    __hip_bfloat16* Bhht  = (__hip_bfloat16*)take((size_t)768*256*2);
    float*          bias3 = (float*)take((size_t)1024*4);
    __hip_bfloat16* hprev_bf = (__hip_bfloat16*)take((size_t)N_NODES*256*2);
    // P1: max(A1 N*640, h2 N*256, hatt N*256, gh N*768) bf16
    char* P1 = take((size_t)N_NODES*768*2);
    // P2: max(A2 N*1280, qkvs N*1024, gi N*768) bf16
    char* P2 = take((size_t)N_NODES*1280*2);

    __hip_bfloat16* A1   = (__hip_bfloat16*)P1;   // [N,640]  dead after gemm1
    __hip_bfloat16* h2   = (__hip_bfloat16*)P1;   // [N,256]  dead after gemm3
    __hip_bfloat16* hatt = (__hip_bfloat16*)P1;   // [N,256]  dead after gemm4
    __hip_bfloat16* gh   = (__hip_bfloat16*)P1;   // [N,768]  written gemm5
    __hip_bfloat16* A2   = (__hip_bfloat16*)P2;   // [N,1280] dead after gemm2
    __hip_bfloat16* qkvs = (__hip_bfloat16*)P2;   // [N,1024] dead after attn_agg
    __hip_bfloat16* gi   = (__hip_bfloat16*)P2;   // [N,768]  written gemm4

    hipMemsetAsync(cnt, 0, (size_t)NRKEYS*4, stream);
    count_kernel<<<(E_EDGES+255)/256, 256, 0, stream>>>(edge_index, edge_type, cnt);
    scan_reduce_kernel<<<SCAN_BLOCKS, 1024, 0, stream>>>(cnt, blocksum);
    scan_sums_kernel<<<1, 128, 0, stream>>>(blocksum, blockoff);
    scan_apply_kernel<<<SCAN_BLOCKS, 1024, 0, stream>>>(cnt, blockoff, row_ptr, cursor);
    fill_kernel<<<(E_EDGES+255)/256, 256, 0, stream>>>(edge_index, edge_type, cursor, csr_src, csr_dst);

    make_b1t<<<(256*640+255)/256, 256, 0, stream>>>(root1, W1, B1t);
    make_b2t<<<(256*1280+255)/256, 256, 0, stream>>>(root2, W2, B2t);
    make_b3t<<<(1024*256+255)/256, 256, 0, stream>>>(Wq, Wk, Wv, Wskip, bq, bk, bv, bskip, B3t, bias3);
    cvt_f32_bf16<<<(768*256+255)/256, 256, 0, stream>>>(W_ih, Biht, 768*256);
    cvt_f32_bf16<<<(768*256+255)/256, 256, 0, stream>>>(W_hh, Bhht, 768*256);
    cvt_f32_bf16<<<(N_NODES*256+255)/256, 256, 0, stream>>>(hprev, hprev_bf, N_NODES*256);

    // one wave per (node,rel) key; block covers node's 4 rels
    agg1_kernel<<<NRKEYS/4, 256, 0, stream>>>(x, row_ptr, csr_src, A1);

    dim3 g12(157, 2);
    // h1 = relu(A1 * B1) written into A2 cols 0..255 (ldc=1280)
    gemm_bt<<<g12, 256, 0, stream>>>(A1, 640, B1t, b1, A2, 1280, N_NODES, 640, 1);

    agg2_kernel<<<NRKEYS/4, 256, 0, stream>>>(row_ptr, csr_src, A2);

    // h2 overwrites A1 (dead) in P1
    gemm_bt<<<g12, 256, 0, stream>>>(A2, 1280, B2t, b2, h2, 256, N_NODES, 1280, 1);

    // qkvs overwrites A2 (dead) in P2
    dim3 g3(157, 8);
    gemm_bt<<<g3, 256, 0, stream>>>(h2, 256, B3t, bias3, qkvs, 1024, N_NODES, 256, 0);

    // attention: CSR-position-parallel scores, then per-(node,head) aggregate
    score_kernel<<<E_EDGES/4, 256, 0, stream>>>(qkvs, csr_src, csr_dst, score);
    attn_agg_kernel<<<N_NODES, 256, 0, stream>>>(qkvs, score, row_ptr, csr_src, hatt);

    dim3 g45(157, 6);
    // gi overwrites qkvs (dead) in P2 -- must run before gemm5
    gemm_bt<<<g45, 256, 0, stream>>>(hatt,     256, Biht, b_ih, gi, 768, N_NODES, 256, 0);
    // gh overwrites hatt (dead) in P1
    gemm_bt<<<g45, 256, 0, stream>>>(hprev_bf, 256, Bhht, b_hh, gh, 768, N_NODES, 256, 0);

    gru_kernel<<<(N_NODES*HIDF+255)/256, 256, 0, stream>>>(gi, gh, hprev, (float*)d_out);
}

// Round 8
// 544.248 us; speedup vs baseline: 1.1559x; 1.0170x over previous
//
#include <hip/hip_runtime.h>
#include <hip/hip_bf16.h>
#include <stdint.h>

#define N_NODES 20000
#define E_EDGES 320000
#define IN_F    128
#define HIDF    256
#define R_REL   4
#define NRKEYS  (N_NODES*R_REL)   // 80000
#define SCAN_BLOCKS 80            // 80*1024 = 81920 >= NRKEYS

typedef __attribute__((ext_vector_type(8))) short  short8;
typedef __attribute__((ext_vector_type(4))) float  floatx4;

__device__ __forceinline__ float bf2f(__hip_bfloat16 v){ return __bfloat162float(v); }
__device__ __forceinline__ __hip_bfloat16 f2bf(float v){ return __float2bfloat16(v); }
__device__ __forceinline__ float bfbits2f(unsigned short u){ return __uint_as_float(((unsigned)u)<<16); }
__device__ __forceinline__ unsigned short f2bfbits(float v){
    __hip_bfloat16 h = __float2bfloat16(v);
    return *(unsigned short*)&h;
}
__device__ __forceinline__ unsigned pack_bf2(float a, float b){
    return (unsigned)f2bfbits(a) | ((unsigned)f2bfbits(b) << 16);
}

// ---------------- CSR build ----------------
__global__ void count_kernel(const int* __restrict__ ei, const int* __restrict__ et,
                             int* __restrict__ cnt)
{
    int e = blockIdx.x*256 + threadIdx.x;
    if (e >= E_EDGES) return;
    int dst = ei[E_EDGES + e];
    atomicAdd(&cnt[dst*R_REL + et[e]], 1);
}

// 3-phase parallel exclusive scan over cnt[NRKEYS] -> row_ptr, cursor
__global__ __launch_bounds__(1024) void scan_reduce_kernel(const int* __restrict__ cnt,
                                                           int* __restrict__ blocksum)
{
    int ix = blockIdx.x*1024 + threadIdx.x;
    int v = (ix < NRKEYS) ? cnt[ix] : 0;
    #pragma unroll
    for (int o=32;o>0;o>>=1) v += __shfl_xor(v, o, 64);
    __shared__ int wsum[16];
    int wave = threadIdx.x >> 6, lane = threadIdx.x & 63;
    if (lane == 0) wsum[wave] = v;
    __syncthreads();
    if (threadIdx.x == 0) {
        int s = 0;
        #pragma unroll
        for (int w=0;w<16;w++) s += wsum[w];
        blocksum[blockIdx.x] = s;
    }
}

__global__ __launch_bounds__(128) void scan_sums_kernel(const int* __restrict__ blocksum,
                                                        int* __restrict__ blockoff)
{
    __shared__ int s[128];
    int t = threadIdx.x;
    int v = (t < SCAN_BLOCKS) ? blocksum[t] : 0;
    s[t] = v; __syncthreads();
    for (int off=1; off<128; off<<=1) {
        int u = (t>=off) ? s[t-off] : 0;
        __syncthreads();
        s[t] += u;
        __syncthreads();
    }
    if (t < SCAN_BLOCKS) blockoff[t] = s[t] - v;   // exclusive
}

__global__ __launch_bounds__(1024) void scan_apply_kernel(const int* __restrict__ cnt,
                                                          const int* __restrict__ blockoff,
                                                          int* __restrict__ row_ptr,
                                                          int* __restrict__ cursor)
{
    __shared__ int s[1024];
    int t = threadIdx.x;
    int ix = blockIdx.x*1024 + t;
    int v = (ix < NRKEYS) ? cnt[ix] : 0;
    s[t] = v; __syncthreads();
    for (int off=1; off<1024; off<<=1) {
        int u = (t>=off) ? s[t-off] : 0;
        __syncthreads();
        s[t] += u;
        __syncthreads();
    }
    if (ix < NRKEYS) {
        int excl = blockoff[blockIdx.x] + s[t] - v;
        row_ptr[ix] = excl;
        cursor[ix]  = excl;
        if (ix == NRKEYS-1) row_ptr[NRKEYS] = excl + v;
    }
}

// records BOTH endpoints per CSR position (position-indexed downstream)
__global__ void fill_kernel(const int* __restrict__ ei, const int* __restrict__ et,
                            int* __restrict__ cursor,
                            int* __restrict__ csr_src, int* __restrict__ csr_dst)
{
    int e = blockIdx.x*256 + threadIdx.x;
    if (e >= E_EDGES) return;
    int src = ei[e];
    int dst = ei[E_EDGES + e];
    int key = dst*R_REL + et[e];
    int pos = atomicAdd(&cursor[key], 1);
    csr_src[pos] = src;
    csr_dst[pos] = dst;
}

// ---------------- weight prep: fp32 sources -> bf16 B^T = [Nout][K] ----------------
__global__ void make_b1t(const float* __restrict__ root1,
                         const float* __restrict__ W1,
                         __hip_bfloat16* __restrict__ B1t)
{
    int idx = blockIdx.x*256 + threadIdx.x;         // n*640 + k
    if (idx >= 256*640) return;
    int n = idx / 640, k = idx % 640;
    float v;
    if (k < 128) v = root1[k*256 + n];
    else         v = W1[(k-128)*256 + n];           // W1 contiguous [R*128][256]
    B1t[idx] = f2bf(v);
}

__global__ void make_b2t(const float* __restrict__ root2,
                         const float* __restrict__ W2,
                         __hip_bfloat16* __restrict__ B2t)
{
    int idx = blockIdx.x*256 + threadIdx.x;         // n*1280 + k
    if (idx >= 256*1280) return;
    int n = idx / 1280, k = idx % 1280;
    float v;
    if (k < 256) v = root2[k*256 + n];
    else         v = W2[(k-256)*256 + n];           // W2 contiguous [R*256][256]
    B2t[idx] = f2bf(v);
}

__global__ void make_b3t(const float* __restrict__ Wq, const float* __restrict__ Wk,
                         const float* __restrict__ Wv, const float* __restrict__ Wsk,
                         const float* __restrict__ bq, const float* __restrict__ bk,
                         const float* __restrict__ bv, const float* __restrict__ bsk,
                         __hip_bfloat16* __restrict__ B3t, float* __restrict__ bias3)
{
    int idx = blockIdx.x*256 + threadIdx.x;         // n*256 + k, n<1024
    if (idx >= 1024*256) return;
    int n = idx / 256, k = idx % 256;
    int g = n >> 8, nn = n & 255;
    const float* W = (g==0)?Wq:(g==1)?Wk:(g==2)?Wv:Wsk;
    B3t[idx] = f2bf(W[k*256 + nn]);
    if (k == 0) {
        const float* B = (g==0)?bq:(g==1)?bk:(g==2)?bv:bsk;
        bias3[n] = B[nn];
    }
}

// generic fp32 -> bf16 elementwise convert (layout-preserving)
__global__ void cvt_f32_bf16(const float* __restrict__ in, __hip_bfloat16* __restrict__ out, int n)
{
    int i = blockIdx.x*256 + threadIdx.x;
    if (i < n) out[i] = f2bf(in[i]);
}

// ---------------- RGCN aggregation: one WAVE per (node,rel) key, unroll-4 ILP ----------------
// agg1: x fp32 [N,128]; lane covers dims 2*lane..2*lane+1 (float2, 8 B)
__global__ __launch_bounds__(256) void agg1_kernel(const float* __restrict__ x,
                                                   const int* __restrict__ row_ptr,
                                                   const int* __restrict__ csr_src,
                                                   __hip_bfloat16* __restrict__ A1)
{
    int b = blockIdx.x*4 + (threadIdx.x >> 6);   // key = i*4 + r
    int lane = threadIdx.x & 63;
    int i = b >> 2, r = b & 3;
    int e0 = row_ptr[b], e1 = row_ptr[b+1];
    float sx0=0.f,sy0=0.f, sx1=0.f,sy1=0.f, sx2=0.f,sy2=0.f, sx3=0.f,sy3=0.f;
    int e = e0;
    for (; e+4 <= e1; e += 4) {
        int i0=csr_src[e], i1=csr_src[e+1], i2=csr_src[e+2], i3=csr_src[e+3];
        float2 v0 = *(const float2*)(x + (size_t)i0*IN_F + lane*2);
        float2 v1 = *(const float2*)(x + (size_t)i1*IN_F + lane*2);
        float2 v2 = *(const float2*)(x + (size_t)i2*IN_F + lane*2);
        float2 v3 = *(const float2*)(x + (size_t)i3*IN_F + lane*2);
        sx0+=v0.x; sy0+=v0.y; sx1+=v1.x; sy1+=v1.y;
        sx2+=v2.x; sy2+=v2.y; sx3+=v3.x; sy3+=v3.y;
    }
    for (; e < e1; e++) {
        int i0 = csr_src[e];
        float2 v = *(const float2*)(x + (size_t)i0*IN_F + lane*2);
        sx0+=v.x; sy0+=v.y;
    }
    float sx = (sx0+sx1)+(sx2+sx3);
    float sy = (sy0+sy1)+(sy2+sy3);
    float inv = (e1>e0) ? 1.f/(float)(e1-e0) : 0.f;
    *(unsigned*)(A1 + (size_t)i*640 + 128 + r*128 + lane*2) = pack_bf2(sx*inv, sy*inv);
    if (r == 0) {
        float2 v = *(const float2*)(x + (size_t)i*IN_F + lane*2);
        *(unsigned*)(A1 + (size_t)i*640 + lane*2) = pack_bf2(v.x, v.y);
    }
}

// agg2: h1 bf16 in A2 cols 0..255 (ld 1280); lane covers dims 4*lane..4*lane+3 (ushort4, 8 B)
__global__ __launch_bounds__(256) void agg2_kernel(const int* __restrict__ row_ptr,
                                                   const int* __restrict__ csr_src,
                                                   __hip_bfloat16* __restrict__ A2)
{
    int b = blockIdx.x*4 + (threadIdx.x >> 6);
    int lane = threadIdx.x & 63;
    int i = b >> 2, r = b & 3;
    int e0 = row_ptr[b], e1 = row_ptr[b+1];
    float a0=0.f,a1=0.f,a2=0.f,a3=0.f;   // slot 0 dims
    float b0=0.f,b1=0.f,b2=0.f,b3=0.f;   // slot 1
    float c0=0.f,c1=0.f,c2=0.f,c3=0.f;   // slot 2
    float d0=0.f,d1=0.f,d2=0.f,d3=0.f;   // slot 3
    int e = e0;
    for (; e+4 <= e1; e += 4) {
        int i0=csr_src[e], i1=csr_src[e+1], i2=csr_src[e+2], i3=csr_src[e+3];
        ushort4 u0 = *(const ushort4*)(A2 + (size_t)i0*1280 + lane*4);
        ushort4 u1 = *(const ushort4*)(A2 + (size_t)i1*1280 + lane*4);
        ushort4 u2 = *(const ushort4*)(A2 + (size_t)i2*1280 + lane*4);
        ushort4 u3 = *(const ushort4*)(A2 + (size_t)i3*1280 + lane*4);
        a0+=bfbits2f(u0.x); a1+=bfbits2f(u0.y); a2+=bfbits2f(u0.z); a3+=bfbits2f(u0.w);
        b0+=bfbits2f(u1.x); b1+=bfbits2f(u1.y); b2+=bfbits2f(u1.z); b3+=bfbits2f(u1.w);
        c0+=bfbits2f(u2.x); c1+=bfbits2f(u2.y); c2+=bfbits2f(u2.z); c3+=bfbits2f(u2.w);
        d0+=bfbits2f(u3.x); d1+=bfbits2f(u3.y); d2+=bfbits2f(u3.z); d3+=bfbits2f(u3.w);
    }
    for (; e < e1; e++) {
        int i0 = csr_src[e];
        ushort4 u = *(const ushort4*)(A2 + (size_t)i0*1280 + lane*4);
        a0+=bfbits2f(u.x); a1+=bfbits2f(u.y); a2+=bfbits2f(u.z); a3+=bfbits2f(u.w);
    }
    float s0=(a0+b0)+(c0+d0), s1=(a1+b1)+(c1+d1), s2=(a2+b2)+(c2+d2), s3=(a3+b3)+(c3+d3);
    float inv = (e1>e0) ? 1.f/(float)(e1-e0) : 0.f;
    uint2 w;
    w.x = pack_bf2(s0*inv, s1*inv);
    w.y = pack_bf2(s2*inv, s3*inv);
    *(uint2*)(A2 + (size_t)i*1280 + 256 + r*256 + lane*4) = w;
}

// ---------------- MFMA GEMM: C[M x Nout] = act(A[M x K] * Bt[Nout x K]^T + bias) ----------------
__global__ __launch_bounds__(256) void gemm_bt(const __hip_bfloat16* __restrict__ A, int lda,
                                               const __hip_bfloat16* __restrict__ Bt,
                                               const float* __restrict__ bias,
                                               __hip_bfloat16* __restrict__ C, int ldc,
                                               int M, int K, int relu)
{
    __shared__ __align__(16) __hip_bfloat16 lds_a[128*32];
    __shared__ __align__(16) __hip_bfloat16 lds_b[128*32];
    const int tid    = threadIdx.x;
    const int tile_m = blockIdx.x * 128;
    const int tile_n = blockIdx.y * 128;
    const int wave   = tid >> 6;
    const int lane   = tid & 63;
    const int wm = wave >> 1, wn = wave & 1;     // 2x2 wave grid: 64x64 each
    const int fm = lane & 15;                    // frag m (A) / n (Bt) / col (C)
    const int q  = lane >> 4;                    // 0..3

    floatx4 acc[4][4];
    #pragma unroll
    for (int i=0;i<4;i++)
        #pragma unroll
        for (int j=0;j<4;j++) acc[i][j] = (floatx4){0.f,0.f,0.f,0.f};

    const int srow   = tid >> 2;                 // 0..63 (plus 64 per pass)
    const int schunk = (tid & 3) * 8;            // element offset along K

    for (int k0 = 0; k0 < K; k0 += 32) {
        __syncthreads();
        #pragma unroll
        for (int p=0;p<2;p++) {
            int row = p*64 + srow;
            int ga  = min(tile_m + row, M-1);    // clamp: pad rows read row M-1 (discarded)
            uint4 v = *(const uint4*)(A + (size_t)ga*lda + k0 + schunk);
            *(uint4*)(&lds_a[row*32 + schunk]) = v;
        }
        #pragma unroll
        for (int p=0;p<2;p++) {
            int row = p*64 + srow;
            uint4 v = *(const uint4*)(Bt + (size_t)(tile_n + row)*K + k0 + schunk);
            *(uint4*)(&lds_b[row*32 + schunk]) = v;
        }
        __syncthreads();

        short8 afr[4], bfr[4];
        #pragma unroll
        for (int i=0;i<4;i++) {
            afr[i] = *(const short8*)(&lds_a[(wm*64 + i*16 + fm)*32 + q*8]);
            bfr[i] = *(const short8*)(&lds_b[(wn*64 + i*16 + fm)*32 + q*8]);
        }
        #pragma unroll
        for (int i=0;i<4;i++)
            #pragma unroll
            for (int j=0;j<4;j++)
                acc[i][j] = __builtin_amdgcn_mfma_f32_16x16x32_bf16(afr[i], bfr[j], acc[i][j], 0,0,0);
    }

    const int crow_base = tile_m + wm*64;
    const int ccol_base = tile_n + wn*64;
    #pragma unroll
    for (int i=0;i<4;i++) {
        #pragma unroll
        for (int j=0;j<4;j++) {
            int c  = ccol_base + j*16 + fm;
            float bb = bias[c];
            #pragma unroll
            for (int rg=0; rg<4; rg++) {
                int r = crow_base + i*16 + q*4 + rg;
                if (r < M) {
                    float v = acc[i][j][rg] + bb;
                    if (relu) v = fmaxf(v, 0.f);
                    C[(size_t)r*ldc + c] = f2bf(v);
                }
            }
        }
    }
}

// ---------------- attention scores (CSR-position-parallel, one wave per position) ----------------
// score layout: [HEADS][E] planes, indexed by CSR POSITION (matches attn_agg reads).
__global__ __launch_bounds__(256) void score_kernel(const __hip_bfloat16* __restrict__ qkvs,
                                                    const int* __restrict__ csr_src,
                                                    const int* __restrict__ csr_dst,
                                                    float* __restrict__ score)
{
    int p = blockIdx.x*4 + (threadIdx.x >> 6);
    if (p >= E_EDGES) return;
    int lane = threadIdx.x & 63;
    int src = csr_src[p], dst = csr_dst[p];
    // lane covers dims 4*lane .. 4*lane+3 of the 256-dim q/k rows; head = lane/16
    const ushort4 qv = *(const ushort4*)(qkvs + (size_t)dst*1024 + lane*4);
    const ushort4 kv = *(const ushort4*)(qkvs + (size_t)src*1024 + 256 + lane*4);
    float d = bfbits2f(qv.x)*bfbits2f(kv.x) + bfbits2f(qv.y)*bfbits2f(kv.y)
            + bfbits2f(qv.z)*bfbits2f(kv.z) + bfbits2f(qv.w)*bfbits2f(kv.w);
    #pragma unroll
    for (int o=1;o<16;o<<=1) d += __shfl_xor(d, o, 64);
    if ((lane & 15) == 0)
        score[(size_t)(lane >> 4)*E_EDGES + p] = d * 0.125f;   // 1/sqrt(64)
}

// ---------------- attention aggregate (one wave per (node, head)) ----------------
// Pass 3 lane split: lane = 16*eg + d4. Edge subgroup eg in [0,4) takes every
// 4th edge; d4 in [0,16) covers the head's 64 dims as ushort4 (8 B) loads.
// 4 independent 128 B gathers in flight per round; per-lane weight recompute
// (broadcast score load + exp) kills the per-edge shfl chain of the old version.
__global__ __launch_bounds__(256) void attn_agg_kernel(const __hip_bfloat16* __restrict__ qkvs,
                                                       const float* __restrict__ score,
                                                       const int* __restrict__ row_ptr,
                                                       const int* __restrict__ csr_src,
                                                       __hip_bfloat16* __restrict__ hatt)
{
    int i = blockIdx.x;
    int h = threadIdx.x >> 6;
    int l = threadIdx.x & 63;
    int eg = l >> 4;              // edge subgroup
    int d4 = l & 15;              // dim quad within head
    int e0 = row_ptr[i*R_REL], e1 = row_ptr[i*R_REL + R_REL];
    int deg = e1 - e0;
    const float* sp = score + (size_t)h*E_EDGES;

    // pass 1: max (lanes = edges)
    float m = -1e30f;
    for (int b = 0; b < deg; b += 64) {
        int j = b + l;
        float sc = (j < deg) ? sp[e0 + j] : -1e30f;
        m = fmaxf(m, sc);
    }
    #pragma unroll
    for (int o=32;o>0;o>>=1) m = fmaxf(m, __shfl_xor(m, o, 64));

    // pass 2: denom
    float ssum = 0.f;
    for (int b = 0; b < deg; b += 64) {
        int j = b + l;
        if (j < deg) ssum += __expf(sp[e0 + j] - m);
    }
    #pragma unroll
    for (int o=32;o>0;o>>=1) ssum += __shfl_xor(ssum, o, 64);
    float inv = 1.f / fmaxf(ssum, 1e-16f);

    // pass 3: 4 edges in parallel; index-clamp + zero-weight for the tail
    float ax=0.f, ay=0.f, az=0.f, aw=0.f;
    for (int t = 0; t < deg; t += 4) {
        int j = t + eg;
        int jc = min(j, deg-1);                 // deg>0 inside this loop
        float w = (j < deg) ? __expf(sp[e0 + jc] - m) * inv : 0.f;
        int s = csr_src[e0 + jc];
        ushort4 u = *(const ushort4*)(qkvs + (size_t)s*1024 + 512 + h*64 + d4*4);
        ax += w*bfbits2f(u.x); ay += w*bfbits2f(u.y);
        az += w*bfbits2f(u.z); aw += w*bfbits2f(u.w);
    }
    // reduce across the 4 edge subgroups (lanes with same d4)
    #pragma unroll
    for (int o=16;o<=32;o<<=1) {
        ax += __shfl_xor(ax, o, 64); ay += __shfl_xor(ay, o, 64);
        az += __shfl_xor(az, o, 64); aw += __shfl_xor(aw, o, 64);
    }
    if (eg == 0) {
        ushort4 sk = *(const ushort4*)(qkvs + (size_t)i*1024 + 768 + h*64 + d4*4);
        uint2 w;
        w.x = pack_bf2(ax + bfbits2f(sk.x), ay + bfbits2f(sk.y));
        w.y = pack_bf2(az + bfbits2f(sk.z), aw + bfbits2f(sk.w));
        *(uint2*)(hatt + (size_t)i*256 + h*64 + d4*4) = w;
    }
}

// ---------------- GRU elementwise (bf16 gates, fp32 math, fp32 out) ----------------
__global__ void gru_kernel(const __hip_bfloat16* __restrict__ gi,
                           const __hip_bfloat16* __restrict__ gh,
                           const float* __restrict__ hprev,
                           float* __restrict__ out)
{
    int idx = blockIdx.x*256 + threadIdx.x;
    if (idx >= N_NODES*HIDF) return;
    int i = idx / HIDF, c = idx % HIDF;
    size_t gb = (size_t)i*768;
    float ir = bf2f(gi[gb + c]), iz = bf2f(gi[gb + 256 + c]), in = bf2f(gi[gb + 512 + c]);
    float hr = bf2f(gh[gb + c]), hz = bf2f(gh[gb + 256 + c]), hn = bf2f(gh[gb + 512 + c]);
    float r = 1.f/(1.f + __expf(-(ir+hr)));
    float z = 1.f/(1.f + __expf(-(iz+hz)));
    float n = tanhf(in + r*hn);
    float h = hprev[idx];
    out[idx] = (1.f - z)*n + z*h;
}

// ---------------- launch ----------------
// Inputs fp32 (verified round 3); bf16 internally for MFMA. Workspace ~102 MB:
//   P1 (30.72 MB): A1 -> h2 -> hatt -> gh
//   P2 (51.2  MB): A2 -> qkvs -> gi
// Ordering: gemm4 (reads hatt, writes gi) BEFORE gemm5 (writes gh over hatt).
extern "C" void kernel_launch(void* const* d_in, const int* in_sizes, int n_in,
                              void* d_out, int out_size, void* d_ws, size_t ws_size,
                              hipStream_t stream)
{
    const float* x       = (const float*)d_in[0];
    const int* edge_index= (const int*)d_in[1];
    const int* edge_type = (const int*)d_in[2];
    const float* hprev   = (const float*)d_in[3];
    const float* W1      = (const float*)d_in[4];
    const float* root1   = (const float*)d_in[5];
    const float* b1      = (const float*)d_in[6];
    const float* W2      = (const float*)d_in[7];
    const float* root2   = (const float*)d_in[8];
    const float* b2      = (const float*)d_in[9];
    const float* Wq      = (const float*)d_in[10];
    const float* bq      = (const float*)d_in[11];
    const float* Wk      = (const float*)d_in[12];
    const float* bk      = (const float*)d_in[13];
    const float* Wv      = (const float*)d_in[14];
    const float* bv      = (const float*)d_in[15];
    const float* Wskip   = (const float*)d_in[16];
    const float* bskip   = (const float*)d_in[17];
    const float* W_ih    = (const float*)d_in[18];
    const float* b_ih    = (const float*)d_in[19];
    const float* W_hh    = (const float*)d_in[20];
    const float* b_hh    = (const float*)d_in[21];

    char* ws = (char*)d_ws;
    size_t off = 0;
    auto take = [&](size_t bytes)->char* {
        char* p = ws + off;
        off = (off + bytes + 255) & ~(size_t)255;
        return p;
    };
    int* cnt        = (int*)take((size_t)NRKEYS*4);
    int* row_ptr    = (int*)take((size_t)(NRKEYS+1)*4);
    int* cursor     = (int*)take((size_t)NRKEYS*4);
    int* csr_src    = (int*)take((size_t)E_EDGES*4);
    int* csr_dst    = (int*)take((size_t)E_EDGES*4);
    int* blocksum   = (int*)take((size_t)SCAN_BLOCKS*4);
    int* blockoff   = (int*)take((size_t)(SCAN_BLOCKS+1)*4);
    float* score    = (float*)take((size_t)R_REL*E_EDGES*4);   // [HEADS][E], CSR-position-indexed
    __hip_bfloat16* B1t   = (__hip_bfloat16*)take((size_t)256*640*2);
    __hip_bfloat16* B2t   = (__hip_bfloat16*)take((size_t)256*1280*2);
    __hip_bfloat16* B3t   = (__hip_bfloat16*)take((size_t)1024*256*2);
    __hip_bfloat16* Biht  = (__hip_bfloat16*)take((size_t)768*256*2);
    __hip_bfloat16* Bhht  = (__hip_bfloat16*)take((size_t)768*256*2);
    float*          bias3 = (float*)take((size_t)1024*4);
    __hip_bfloat16* hprev_bf = (__hip_bfloat16*)take((size_t)N_NODES*256*2);
    // P1: max(A1 N*640, h2 N*256, hatt N*256, gh N*768) bf16
    char* P1 = take((size_t)N_NODES*768*2);
    // P2: max(A2 N*1280, qkvs N*1024, gi N*768) bf16
    char* P2 = take((size_t)N_NODES*1280*2);

    __hip_bfloat16* A1   = (__hip_bfloat16*)P1;   // [N,640]  dead after gemm1
    __hip_bfloat16* h2   = (__hip_bfloat16*)P1;   // [N,256]  dead after gemm3
    __hip_bfloat16* hatt = (__hip_bfloat16*)P1;   // [N,256]  dead after gemm4
    __hip_bfloat16* gh   = (__hip_bfloat16*)P1;   // [N,768]  written gemm5
    __hip_bfloat16* A2   = (__hip_bfloat16*)P2;   // [N,1280] dead after gemm2
    __hip_bfloat16* qkvs = (__hip_bfloat16*)P2;   // [N,1024] dead after attn_agg
    __hip_bfloat16* gi   = (__hip_bfloat16*)P2;   // [N,768]  written gemm4

    hipMemsetAsync(cnt, 0, (size_t)NRKEYS*4, stream);
    count_kernel<<<(E_EDGES+255)/256, 256, 0, stream>>>(edge_index, edge_type, cnt);
    scan_reduce_kernel<<<SCAN_BLOCKS, 1024, 0, stream>>>(cnt, blocksum);
    scan_sums_kernel<<<1, 128, 0, stream>>>(blocksum, blockoff);
    scan_apply_kernel<<<SCAN_BLOCKS, 1024, 0, stream>>>(cnt, blockoff, row_ptr, cursor);
    fill_kernel<<<(E_EDGES+255)/256, 256, 0, stream>>>(edge_index, edge_type, cursor, csr_src, csr_dst);

    make_b1t<<<(256*640+255)/256, 256, 0, stream>>>(root1, W1, B1t);
    make_b2t<<<(256*1280+255)/256, 256, 0, stream>>>(root2, W2, B2t);
    make_b3t<<<(1024*256+255)/256, 256, 0, stream>>>(Wq, Wk, Wv, Wskip, bq, bk, bv, bskip, B3t, bias3);
    cvt_f32_bf16<<<(768*256+255)/256, 256, 0, stream>>>(W_ih, Biht, 768*256);
    cvt_f32_bf16<<<(768*256+255)/256, 256, 0, stream>>>(W_hh, Bhht, 768*256);
    cvt_f32_bf16<<<(N_NODES*256+255)/256, 256, 0, stream>>>(hprev, hprev_bf, N_NODES*256);

    // one wave per (node,rel) key; block covers node's 4 rels
    agg1_kernel<<<NRKEYS/4, 256, 0, stream>>>(x, row_ptr, csr_src, A1);

    dim3 g12(157, 2);
    // h1 = relu(A1 * B1) written into A2 cols 0..255 (ldc=1280)
    gemm_bt<<<g12, 256, 0, stream>>>(A1, 640, B1t, b1, A2, 1280, N_NODES, 640, 1);

    agg2_kernel<<<NRKEYS/4, 256, 0, stream>>>(row_ptr, csr_src, A2);

    // h2 overwrites A1 (dead) in P1
    gemm_bt<<<g12, 256, 0, stream>>>(A2, 1280, B2t, b2, h2, 256, N_NODES, 1280, 1);

    // qkvs overwrites A2 (dead) in P2
    dim3 g3(157, 8);
    gemm_bt<<<g3, 256, 0, stream>>>(h2, 256, B3t, bias3, qkvs, 1024, N_NODES, 256, 0);

    // attention: CSR-position-parallel scores, then per-(node,head) aggregate
    score_kernel<<<E_EDGES/4, 256, 0, stream>>>(qkvs, csr_src, csr_dst, score);
    attn_agg_kernel<<<N_NODES, 256, 0, stream>>>(qkvs, score, row_ptr, csr_src, hatt);

    dim3 g45(157, 6);
    // gi overwrites qkvs (dead) in P2 -- must run before gemm5
    gemm_bt<<<g45, 256, 0, stream>>>(hatt,     256, Biht, b_ih, gi, 768, N_NODES, 256, 0);
    // gh overwrites hatt (dead) in P1
    gemm_bt<<<g45, 256, 0, stream>>>(hprev_bf, 256, Bhht, b_hh, gh, 768, N_NODES, 256, 0);

    gru_kernel<<<(N_NODES*HIDF+255)/256, 256, 0, stream>>>(gi, gh, hprev, (float*)d_out);
}

// Round 9
// 500.639 us; speedup vs baseline: 1.2566x; 1.0871x over previous
//
#include <hip/hip_runtime.h>
#include <hip/hip_bf16.h>
#include <stdint.h>

#define N_NODES 20000
#define E_EDGES 320000
#define IN_F    128
#define HIDF    256
#define R_REL   4
#define NRKEYS  (N_NODES*R_REL)   // 80000
#define SCAN_BLOCKS 80            // 80*1024 = 81920 >= NRKEYS

typedef __attribute__((ext_vector_type(8))) short  short8;
typedef __attribute__((ext_vector_type(4))) float  floatx4;

__device__ __forceinline__ float bf2f(__hip_bfloat16 v){ return __bfloat162float(v); }
__device__ __forceinline__ __hip_bfloat16 f2bf(float v){ return __float2bfloat16(v); }
__device__ __forceinline__ float bfbits2f(unsigned short u){ return __uint_as_float(((unsigned)u)<<16); }
__device__ __forceinline__ unsigned short f2bfbits(float v){
    __hip_bfloat16 h = __float2bfloat16(v);
    return *(unsigned short*)&h;
}
__device__ __forceinline__ unsigned pack_bf2(float a, float b){
    return (unsigned)f2bfbits(a) | ((unsigned)f2bfbits(b) << 16);
}

// ---------------- CSR build ----------------
__global__ void count_kernel(const int* __restrict__ ei, const int* __restrict__ et,
                             int* __restrict__ cnt)
{
    int e = blockIdx.x*256 + threadIdx.x;
    if (e >= E_EDGES) return;
    int dst = ei[E_EDGES + e];
    atomicAdd(&cnt[dst*R_REL + et[e]], 1);
}

// 3-phase parallel exclusive scan over cnt[NRKEYS] -> row_ptr, cursor
__global__ __launch_bounds__(1024) void scan_reduce_kernel(const int* __restrict__ cnt,
                                                           int* __restrict__ blocksum)
{
    int ix = blockIdx.x*1024 + threadIdx.x;
    int v = (ix < NRKEYS) ? cnt[ix] : 0;
    #pragma unroll
    for (int o=32;o>0;o>>=1) v += __shfl_xor(v, o, 64);
    __shared__ int wsum[16];
    int wave = threadIdx.x >> 6, lane = threadIdx.x & 63;
    if (lane == 0) wsum[wave] = v;
    __syncthreads();
    if (threadIdx.x == 0) {
        int s = 0;
        #pragma unroll
        for (int w=0;w<16;w++) s += wsum[w];
        blocksum[blockIdx.x] = s;
    }
}

__global__ __launch_bounds__(128) void scan_sums_kernel(const int* __restrict__ blocksum,
                                                        int* __restrict__ blockoff)
{
    __shared__ int s[128];
    int t = threadIdx.x;
    int v = (t < SCAN_BLOCKS) ? blocksum[t] : 0;
    s[t] = v; __syncthreads();
    for (int off=1; off<128; off<<=1) {
        int u = (t>=off) ? s[t-off] : 0;
        __syncthreads();
        s[t] += u;
        __syncthreads();
    }
    if (t < SCAN_BLOCKS) blockoff[t] = s[t] - v;   // exclusive
}

__global__ __launch_bounds__(1024) void scan_apply_kernel(const int* __restrict__ cnt,
                                                          const int* __restrict__ blockoff,
                                                          int* __restrict__ row_ptr,
                                                          int* __restrict__ cursor)
{
    __shared__ int s[1024];
    int t = threadIdx.x;
    int ix = blockIdx.x*1024 + t;
    int v = (ix < NRKEYS) ? cnt[ix] : 0;
    s[t] = v; __syncthreads();
    for (int off=1; off<1024; off<<=1) {
        int u = (t>=off) ? s[t-off] : 0;
        __syncthreads();
        s[t] += u;
        __syncthreads();
    }
    if (ix < NRKEYS) {
        int excl = blockoff[blockIdx.x] + s[t] - v;
        row_ptr[ix] = excl;
        cursor[ix]  = excl;
        if (ix == NRKEYS-1) row_ptr[NRKEYS] = excl + v;
    }
}

// records BOTH endpoints per CSR position (position-indexed downstream)
__global__ void fill_kernel(const int* __restrict__ ei, const int* __restrict__ et,
                            int* __restrict__ cursor,
                            int* __restrict__ csr_src, int* __restrict__ csr_dst)
{
    int e = blockIdx.x*256 + threadIdx.x;
    if (e >= E_EDGES) return;
    int src = ei[e];
    int dst = ei[E_EDGES + e];
    int key = dst*R_REL + et[e];
    int pos = atomicAdd(&cursor[key], 1);
    csr_src[pos] = src;
    csr_dst[pos] = dst;
}

// ---------------- weight prep: fp32 sources -> bf16 B^T = [Nout][K] ----------------
__global__ void make_b1t(const float* __restrict__ root1,
                         const float* __restrict__ W1,
                         __hip_bfloat16* __restrict__ B1t)
{
    int idx = blockIdx.x*256 + threadIdx.x;         // n*640 + k
    if (idx >= 256*640) return;
    int n = idx / 640, k = idx % 640;
    float v;
    if (k < 128) v = root1[k*256 + n];
    else         v = W1[(k-128)*256 + n];           // W1 contiguous [R*128][256]
    B1t[idx] = f2bf(v);
}

__global__ void make_b2t(const float* __restrict__ root2,
                         const float* __restrict__ W2,
                         __hip_bfloat16* __restrict__ B2t)
{
    int idx = blockIdx.x*256 + threadIdx.x;         // n*1280 + k
    if (idx >= 256*1280) return;
    int n = idx / 1280, k = idx % 1280;
    float v;
    if (k < 256) v = root2[k*256 + n];
    else         v = W2[(k-256)*256 + n];           // W2 contiguous [R*256][256]
    B2t[idx] = f2bf(v);
}

__global__ void make_b3t(const float* __restrict__ Wq, const float* __restrict__ Wk,
                         const float* __restrict__ Wv, const float* __restrict__ Wsk,
                         const float* __restrict__ bq, const float* __restrict__ bk,
                         const float* __restrict__ bv, const float* __restrict__ bsk,
                         __hip_bfloat16* __restrict__ B3t, float* __restrict__ bias3)
{
    int idx = blockIdx.x*256 + threadIdx.x;         // n*256 + k, n<1024
    if (idx >= 1024*256) return;
    int n = idx / 256, k = idx % 256;
    int g = n >> 8, nn = n & 255;
    const float* W = (g==0)?Wq:(g==1)?Wk:(g==2)?Wv:Wsk;
    B3t[idx] = f2bf(W[k*256 + nn]);
    if (k == 0) {
        const float* B = (g==0)?bq:(g==1)?bk:(g==2)?bv:bsk;
        bias3[n] = B[nn];
    }
}

// generic fp32 -> bf16 elementwise convert (layout-preserving)
__global__ void cvt_f32_bf16(const float* __restrict__ in, __hip_bfloat16* __restrict__ out, int n)
{
    int i = blockIdx.x*256 + threadIdx.x;
    if (i < n) out[i] = f2bf(in[i]);
}

// ---------------- RGCN aggregation: one WAVE per (node,rel) key, unroll-4 ILP ----------------
// agg1: x fp32 [N,128]; lane covers dims 2*lane..2*lane+1 (float2, 8 B)
__global__ __launch_bounds__(256) void agg1_kernel(const float* __restrict__ x,
                                                   const int* __restrict__ row_ptr,
                                                   const int* __restrict__ csr_src,
                                                   __hip_bfloat16* __restrict__ A1)
{
    int b = blockIdx.x*4 + (threadIdx.x >> 6);   // key = i*4 + r
    int lane = threadIdx.x & 63;
    int i = b >> 2, r = b & 3;
    int e0 = row_ptr[b], e1 = row_ptr[b+1];
    float sx0=0.f,sy0=0.f, sx1=0.f,sy1=0.f, sx2=0.f,sy2=0.f, sx3=0.f,sy3=0.f;
    int e = e0;
    for (; e+4 <= e1; e += 4) {
        int i0=csr_src[e], i1=csr_src[e+1], i2=csr_src[e+2], i3=csr_src[e+3];
        float2 v0 = *(const float2*)(x + (size_t)i0*IN_F + lane*2);
        float2 v1 = *(const float2*)(x + (size_t)i1*IN_F + lane*2);
        float2 v2 = *(const float2*)(x + (size_t)i2*IN_F + lane*2);
        float2 v3 = *(const float2*)(x + (size_t)i3*IN_F + lane*2);
        sx0+=v0.x; sy0+=v0.y; sx1+=v1.x; sy1+=v1.y;
        sx2+=v2.x; sy2+=v2.y; sx3+=v3.x; sy3+=v3.y;
    }
    for (; e < e1; e++) {
        int i0 = csr_src[e];
        float2 v = *(const float2*)(x + (size_t)i0*IN_F + lane*2);
        sx0+=v.x; sy0+=v.y;
    }
    float sx = (sx0+sx1)+(sx2+sx3);
    float sy = (sy0+sy1)+(sy2+sy3);
    float inv = (e1>e0) ? 1.f/(float)(e1-e0) : 0.f;
    *(unsigned*)(A1 + (size_t)i*640 + 128 + r*128 + lane*2) = pack_bf2(sx*inv, sy*inv);
    if (r == 0) {
        float2 v = *(const float2*)(x + (size_t)i*IN_F + lane*2);
        *(unsigned*)(A1 + (size_t)i*640 + lane*2) = pack_bf2(v.x, v.y);
    }
}

// agg2: h1 bf16 in A2 cols 0..255 (ld 1280); lane covers dims 4*lane..4*lane+3 (ushort4, 8 B)
__global__ __launch_bounds__(256) void agg2_kernel(const int* __restrict__ row_ptr,
                                                   const int* __restrict__ csr_src,
                                                   __hip_bfloat16* __restrict__ A2)
{
    int b = blockIdx.x*4 + (threadIdx.x >> 6);
    int lane = threadIdx.x & 63;
    int i = b >> 2, r = b & 3;
    int e0 = row_ptr[b], e1 = row_ptr[b+1];
    float a0=0.f,a1=0.f,a2=0.f,a3=0.f;   // slot 0 dims
    float b0=0.f,b1=0.f,b2=0.f,b3=0.f;   // slot 1
    float c0=0.f,c1=0.f,c2=0.f,c3=0.f;   // slot 2
    float d0=0.f,d1=0.f,d2=0.f,d3=0.f;   // slot 3
    int e = e0;
    for (; e+4 <= e1; e += 4) {
        int i0=csr_src[e], i1=csr_src[e+1], i2=csr_src[e+2], i3=csr_src[e+3];
        ushort4 u0 = *(const ushort4*)(A2 + (size_t)i0*1280 + lane*4);
        ushort4 u1 = *(const ushort4*)(A2 + (size_t)i1*1280 + lane*4);
        ushort4 u2 = *(const ushort4*)(A2 + (size_t)i2*1280 + lane*4);
        ushort4 u3 = *(const ushort4*)(A2 + (size_t)i3*1280 + lane*4);
        a0+=bfbits2f(u0.x); a1+=bfbits2f(u0.y); a2+=bfbits2f(u0.z); a3+=bfbits2f(u0.w);
        b0+=bfbits2f(u1.x); b1+=bfbits2f(u1.y); b2+=bfbits2f(u1.z); b3+=bfbits2f(u1.w);
        c0+=bfbits2f(u2.x); c1+=bfbits2f(u2.y); c2+=bfbits2f(u2.z); c3+=bfbits2f(u2.w);
        d0+=bfbits2f(u3.x); d1+=bfbits2f(u3.y); d2+=bfbits2f(u3.z); d3+=bfbits2f(u3.w);
    }
    for (; e < e1; e++) {
        int i0 = csr_src[e];
        ushort4 u = *(const ushort4*)(A2 + (size_t)i0*1280 + lane*4);
        a0+=bfbits2f(u.x); a1+=bfbits2f(u.y); a2+=bfbits2f(u.z); a3+=bfbits2f(u.w);
    }
    float s0=(a0+b0)+(c0+d0), s1=(a1+b1)+(c1+d1), s2=(a2+b2)+(c2+d2), s3=(a3+b3)+(c3+d3);
    float inv = (e1>e0) ? 1.f/(float)(e1-e0) : 0.f;
    uint2 w;
    w.x = pack_bf2(s0*inv, s1*inv);
    w.y = pack_bf2(s2*inv, s3*inv);
    *(uint2*)(A2 + (size_t)i*1280 + 256 + r*256 + lane*4) = w;
}

// ---------------- MFMA GEMM: C[M x Nout] = act(A[M x K] * Bt[Nout x K]^T + bias) ----------------
__global__ __launch_bounds__(256) void gemm_bt(const __hip_bfloat16* __restrict__ A, int lda,
                                               const __hip_bfloat16* __restrict__ Bt,
                                               const float* __restrict__ bias,
                                               __hip_bfloat16* __restrict__ C, int ldc,
                                               int M, int K, int relu)
{
    __shared__ __align__(16) __hip_bfloat16 lds_a[128*32];
    __shared__ __align__(16) __hip_bfloat16 lds_b[128*32];
    const int tid    = threadIdx.x;
    const int tile_m = blockIdx.x * 128;
    const int tile_n = blockIdx.y * 128;
    const int wave   = tid >> 6;
    const int lane   = tid & 63;
    const int wm = wave >> 1, wn = wave & 1;     // 2x2 wave grid: 64x64 each
    const int fm = lane & 15;                    // frag m (A) / n (Bt) / col (C)
    const int q  = lane >> 4;                    // 0..3

    floatx4 acc[4][4];
    #pragma unroll
    for (int i=0;i<4;i++)
        #pragma unroll
        for (int j=0;j<4;j++) acc[i][j] = (floatx4){0.f,0.f,0.f,0.f};

    const int srow   = tid >> 2;                 // 0..63 (plus 64 per pass)
    const int schunk = (tid & 3) * 8;            // element offset along K

    for (int k0 = 0; k0 < K; k0 += 32) {
        __syncthreads();
        #pragma unroll
        for (int p=0;p<2;p++) {
            int row = p*64 + srow;
            int ga  = min(tile_m + row, M-1);    // clamp: pad rows read row M-1 (discarded)
            uint4 v = *(const uint4*)(A + (size_t)ga*lda + k0 + schunk);
            *(uint4*)(&lds_a[row*32 + schunk]) = v;
        }
        #pragma unroll
        for (int p=0;p<2;p++) {
            int row = p*64 + srow;
            uint4 v = *(const uint4*)(Bt + (size_t)(tile_n + row)*K + k0 + schunk);
            *(uint4*)(&lds_b[row*32 + schunk]) = v;
        }
        __syncthreads();

        short8 afr[4], bfr[4];
        #pragma unroll
        for (int i=0;i<4;i++) {
            afr[i] = *(const short8*)(&lds_a[(wm*64 + i*16 + fm)*32 + q*8]);
            bfr[i] = *(const short8*)(&lds_b[(wn*64 + i*16 + fm)*32 + q*8]);
        }
        #pragma unroll
        for (int i=0;i<4;i++)
            #pragma unroll
            for (int j=0;j<4;j++)
                acc[i][j] = __builtin_amdgcn_mfma_f32_16x16x32_bf16(afr[i], bfr[j], acc[i][j], 0,0,0);
    }

    const int crow_base = tile_m + wm*64;
    const int ccol_base = tile_n + wn*64;
    #pragma unroll
    for (int i=0;i<4;i++) {
        #pragma unroll
        for (int j=0;j<4;j++) {
            int c  = ccol_base + j*16 + fm;
            float bb = bias[c];
            #pragma unroll
            for (int rg=0; rg<4; rg++) {
                int r = crow_base + i*16 + q*4 + rg;
                if (r < M) {
                    float v = acc[i][j][rg] + bb;
                    if (relu) v = fmaxf(v, 0.f);
                    C[(size_t)r*ldc + c] = f2bf(v);
                }
            }
        }
    }
}

// ---------------- attention scores (CSR-position-parallel, one wave per position) ----------------
// score layout: [HEADS][E] planes, indexed by CSR POSITION (matches attn_agg reads).
__global__ __launch_bounds__(256) void score_kernel(const __hip_bfloat16* __restrict__ qkvs,
                                                    const int* __restrict__ csr_src,
                                                    const int* __restrict__ csr_dst,
                                                    float* __restrict__ score)
{
    int p = blockIdx.x*4 + (threadIdx.x >> 6);
    if (p >= E_EDGES) return;
    int lane = threadIdx.x & 63;
    int src = csr_src[p], dst = csr_dst[p];
    // lane covers dims 4*lane .. 4*lane+3 of the 256-dim q/k rows; head = lane/16
    const ushort4 qv = *(const ushort4*)(qkvs + (size_t)dst*1024 + lane*4);
    const ushort4 kv = *(const ushort4*)(qkvs + (size_t)src*1024 + 256 + lane*4);
    float d = bfbits2f(qv.x)*bfbits2f(kv.x) + bfbits2f(qv.y)*bfbits2f(kv.y)
            + bfbits2f(qv.z)*bfbits2f(kv.z) + bfbits2f(qv.w)*bfbits2f(kv.w);
    #pragma unroll
    for (int o=1;o<16;o<<=1) d += __shfl_xor(d, o, 64);
    if ((lane & 15) == 0)
        score[(size_t)(lane >> 4)*E_EDGES + p] = d * 0.125f;   // 1/sqrt(64)
}

// ---------------- attention aggregate: ONE WAVE PER NODE, all 4 heads ----------------
// lane = h*16 + d4: head h = lane>>4, dim quad d4 = lane&15. Lane owns output
// dims lane*4..lane*4+3 of the 256-dim row, so the per-edge V load is ONE
// contiguous 512 B wave request (vs 4x128 B from 4 head-waves previously) and
// pass 3 needs no cross-lane reduction at all. csr_src/score loads dedup x4.
__global__ __launch_bounds__(256) void attn_agg_kernel(const __hip_bfloat16* __restrict__ qkvs,
                                                       const float* __restrict__ score,
                                                       const int* __restrict__ row_ptr,
                                                       const int* __restrict__ csr_src,
                                                       __hip_bfloat16* __restrict__ hatt)
{
    int i = blockIdx.x*4 + (threadIdx.x >> 6);   // node (4 nodes per block)
    int lane = threadIdx.x & 63;
    int h  = lane >> 4;
    int d4 = lane & 15;
    int e0 = row_ptr[i*R_REL], e1 = row_ptr[i*R_REL + R_REL];
    int deg = e1 - e0;
    const float* sp = score + (size_t)h*E_EDGES + e0;

    // pass 1: per-head max (16 lanes stride the edge list)
    float m = -1e30f;
    for (int j = d4; j < deg; j += 16) m = fmaxf(m, sp[j]);
    #pragma unroll
    for (int o=1;o<16;o<<=1) m = fmaxf(m, __shfl_xor(m, o, 64));

    // pass 2: per-head denom
    float ssum = 0.f;
    for (int j = d4; j < deg; j += 16) ssum += __expf(sp[j] - m);
    #pragma unroll
    for (int o=1;o<16;o<<=1) ssum += __shfl_xor(ssum, o, 64);
    float inv = 1.f / fmaxf(ssum, 1e-16f);

    // pass 3: all lanes walk all edges (unroll 4 -> 4 independent 512 B loads
    // in flight); weight per lane's head, no shfl, no reduction
    float ax=0.f, ay=0.f, az=0.f, aw=0.f;
    int j = 0;
    for (; j+4 <= deg; j += 4) {
        int s0=csr_src[e0+j], s1=csr_src[e0+j+1], s2=csr_src[e0+j+2], s3=csr_src[e0+j+3];
        float w0 = __expf(sp[j]   - m) * inv;
        float w1 = __expf(sp[j+1] - m) * inv;
        float w2 = __expf(sp[j+2] - m) * inv;
        float w3 = __expf(sp[j+3] - m) * inv;
        ushort4 u0 = *(const ushort4*)(qkvs + (size_t)s0*1024 + 512 + lane*4);
        ushort4 u1 = *(const ushort4*)(qkvs + (size_t)s1*1024 + 512 + lane*4);
        ushort4 u2 = *(const ushort4*)(qkvs + (size_t)s2*1024 + 512 + lane*4);
        ushort4 u3 = *(const ushort4*)(qkvs + (size_t)s3*1024 + 512 + lane*4);
        ax += w0*bfbits2f(u0.x) + w1*bfbits2f(u1.x) + w2*bfbits2f(u2.x) + w3*bfbits2f(u3.x);
        ay += w0*bfbits2f(u0.y) + w1*bfbits2f(u1.y) + w2*bfbits2f(u2.y) + w3*bfbits2f(u3.y);
        az += w0*bfbits2f(u0.z) + w1*bfbits2f(u1.z) + w2*bfbits2f(u2.z) + w3*bfbits2f(u3.z);
        aw += w0*bfbits2f(u0.w) + w1*bfbits2f(u1.w) + w2*bfbits2f(u2.w) + w3*bfbits2f(u3.w);
    }
    for (; j < deg; j++) {
        int s = csr_src[e0+j];
        float w = __expf(sp[j] - m) * inv;
        ushort4 u = *(const ushort4*)(qkvs + (size_t)s*1024 + 512 + lane*4);
        ax += w*bfbits2f(u.x); ay += w*bfbits2f(u.y);
        az += w*bfbits2f(u.z); aw += w*bfbits2f(u.w);
    }
    ushort4 sk = *(const ushort4*)(qkvs + (size_t)i*1024 + 768 + lane*4);
    uint2 w;
    w.x = pack_bf2(ax + bfbits2f(sk.x), ay + bfbits2f(sk.y));
    w.y = pack_bf2(az + bfbits2f(sk.z), aw + bfbits2f(sk.w));
    *(uint2*)(hatt + (size_t)i*256 + lane*4) = w;
}

// ---------------- GRU elementwise (bf16 gates, fp32 math, fp32 out) ----------------
__global__ void gru_kernel(const __hip_bfloat16* __restrict__ gi,
                           const __hip_bfloat16* __restrict__ gh,
                           const float* __restrict__ hprev,
                           float* __restrict__ out)
{
    int idx = blockIdx.x*256 + threadIdx.x;
    if (idx >= N_NODES*HIDF) return;
    int i = idx / HIDF, c = idx % HIDF;
    size_t gb = (size_t)i*768;
    float ir = bf2f(gi[gb + c]), iz = bf2f(gi[gb + 256 + c]), in = bf2f(gi[gb + 512 + c]);
    float hr = bf2f(gh[gb + c]), hz = bf2f(gh[gb + 256 + c]), hn = bf2f(gh[gb + 512 + c]);
    float r = 1.f/(1.f + __expf(-(ir+hr)));
    float z = 1.f/(1.f + __expf(-(iz+hz)));
    float n = tanhf(in + r*hn);
    float h = hprev[idx];
    out[idx] = (1.f - z)*n + z*h;
}

// ---------------- launch ----------------
// Inputs fp32 (verified round 3); bf16 internally for MFMA. Workspace ~102 MB:
//   P1 (30.72 MB): A1 -> h2 -> hatt -> gh
//   P2 (51.2  MB): A2 -> qkvs -> gi
// Ordering: gemm4 (reads hatt, writes gi) BEFORE gemm5 (writes gh over hatt).
extern "C" void kernel_launch(void* const* d_in, const int* in_sizes, int n_in,
                              void* d_out, int out_size, void* d_ws, size_t ws_size,
                              hipStream_t stream)
{
    const float* x       = (const float*)d_in[0];
    const int* edge_index= (const int*)d_in[1];
    const int* edge_type = (const int*)d_in[2];
    const float* hprev   = (const float*)d_in[3];
    const float* W1      = (const float*)d_in[4];
    const float* root1   = (const float*)d_in[5];
    const float* b1      = (const float*)d_in[6];
    const float* W2      = (const float*)d_in[7];
    const float* root2   = (const float*)d_in[8];
    const float* b2      = (const float*)d_in[9];
    const float* Wq      = (const float*)d_in[10];
    const float* bq      = (const float*)d_in[11];
    const float* Wk      = (const float*)d_in[12];
    const float* bk      = (const float*)d_in[13];
    const float* Wv      = (const float*)d_in[14];
    const float* bv      = (const float*)d_in[15];
    const float* Wskip   = (const float*)d_in[16];
    const float* bskip   = (const float*)d_in[17];
    const float* W_ih    = (const float*)d_in[18];
    const float* b_ih    = (const float*)d_in[19];
    const float* W_hh    = (const float*)d_in[20];
    const float* b_hh    = (const float*)d_in[21];

    char* ws = (char*)d_ws;
    size_t off = 0;
    auto take = [&](size_t bytes)->char* {
        char* p = ws + off;
        off = (off + bytes + 255) & ~(size_t)255;
        return p;
    };
    int* cnt        = (int*)take((size_t)NRKEYS*4);
    int* row_ptr    = (int*)take((size_t)(NRKEYS+1)*4);
    int* cursor     = (int*)take((size_t)NRKEYS*4);
    int* csr_src    = (int*)take((size_t)E_EDGES*4);
    int* csr_dst    = (int*)take((size_t)E_EDGES*4);
    int* blocksum   = (int*)take((size_t)SCAN_BLOCKS*4);
    int* blockoff   = (int*)take((size_t)(SCAN_BLOCKS+1)*4);
    float* score    = (float*)take((size_t)R_REL*E_EDGES*4);   // [HEADS][E], CSR-position-indexed
    __hip_bfloat16* B1t   = (__hip_bfloat16*)take((size_t)256*640*2);
    __hip_bfloat16* B2t   = (__hip_bfloat16*)take((size_t)256*1280*2);
    __hip_bfloat16* B3t   = (__hip_bfloat16*)take((size_t)1024*256*2);
    __hip_bfloat16* Biht  = (__hip_bfloat16*)take((size_t)768*256*2);
    __hip_bfloat16* Bhht  = (__hip_bfloat16*)take((size_t)768*256*2);
    float*          bias3 = (float*)take((size_t)1024*4);
    __hip_bfloat16* hprev_bf = (__hip_bfloat16*)take((size_t)N_NODES*256*2);
    // P1: max(A1 N*640, h2 N*256, hatt N*256, gh N*768) bf16
    char* P1 = take((size_t)N_NODES*768*2);
    // P2: max(A2 N*1280, qkvs N*1024, gi N*768) bf16
    char* P2 = take((size_t)N_NODES*1280*2);

    __hip_bfloat16* A1   = (__hip_bfloat16*)P1;   // [N,640]  dead after gemm1
    __hip_bfloat16* h2   = (__hip_bfloat16*)P1;   // [N,256]  dead after gemm3
    __hip_bfloat16* hatt = (__hip_bfloat16*)P1;   // [N,256]  dead after gemm4
    __hip_bfloat16* gh   = (__hip_bfloat16*)P1;   // [N,768]  written gemm5
    __hip_bfloat16* A2   = (__hip_bfloat16*)P2;   // [N,1280] dead after gemm2
    __hip_bfloat16* qkvs = (__hip_bfloat16*)P2;   // [N,1024] dead after attn_agg
    __hip_bfloat16* gi   = (__hip_bfloat16*)P2;   // [N,768]  written gemm4

    hipMemsetAsync(cnt, 0, (size_t)NRKEYS*4, stream);
    count_kernel<<<(E_EDGES+255)/256, 256, 0, stream>>>(edge_index, edge_type, cnt);
    scan_reduce_kernel<<<SCAN_BLOCKS, 1024, 0, stream>>>(cnt, blocksum);
    scan_sums_kernel<<<1, 128, 0, stream>>>(blocksum, blockoff);
    scan_apply_kernel<<<SCAN_BLOCKS, 1024, 0, stream>>>(cnt, blockoff, row_ptr, cursor);
    fill_kernel<<<(E_EDGES+255)/256, 256, 0, stream>>>(edge_index, edge_type, cursor, csr_src, csr_dst);

    make_b1t<<<(256*640+255)/256, 256, 0, stream>>>(root1, W1, B1t);
    make_b2t<<<(256*1280+255)/256, 256, 0, stream>>>(root2, W2, B2t);
    make_b3t<<<(1024*256+255)/256, 256, 0, stream>>>(Wq, Wk, Wv, Wskip, bq, bk, bv, bskip, B3t, bias3);
    cvt_f32_bf16<<<(768*256+255)/256, 256, 0, stream>>>(W_ih, Biht, 768*256);
    cvt_f32_bf16<<<(768*256+255)/256, 256, 0, stream>>>(W_hh, Bhht, 768*256);
    cvt_f32_bf16<<<(N_NODES*256+255)/256, 256, 0, stream>>>(hprev, hprev_bf, N_NODES*256);

    // one wave per (node,rel) key; block covers node's 4 rels
    agg1_kernel<<<NRKEYS/4, 256, 0, stream>>>(x, row_ptr, csr_src, A1);

    dim3 g12(157, 2);
    // h1 = relu(A1 * B1) written into A2 cols 0..255 (ldc=1280)
    gemm_bt<<<g12, 256, 0, stream>>>(A1, 640, B1t, b1, A2, 1280, N_NODES, 640, 1);

    agg2_kernel<<<NRKEYS/4, 256, 0, stream>>>(row_ptr, csr_src, A2);

    // h2 overwrites A1 (dead) in P1
    gemm_bt<<<g12, 256, 0, stream>>>(A2, 1280, B2t, b2, h2, 256, N_NODES, 1280, 1);

    // qkvs overwrites A2 (dead) in P2
    dim3 g3(157, 8);
    gemm_bt<<<g3, 256, 0, stream>>>(h2, 256, B3t, bias3, qkvs, 1024, N_NODES, 256, 0);

    // attention: CSR-position-parallel scores, then one-wave-per-node aggregate
    score_kernel<<<E_EDGES/4, 256, 0, stream>>>(qkvs, csr_src, csr_dst, score);
    attn_agg_kernel<<<N_NODES/4, 256, 0, stream>>>(qkvs, score, row_ptr, csr_src, hatt);

    dim3 g45(157, 6);
    // gi overwrites qkvs (dead) in P2 -- must run before gemm5
    gemm_bt<<<g45, 256, 0, stream>>>(hatt,     256, Biht, b_ih, gi, 768, N_NODES, 256, 0);
    // gh overwrites hatt (dead) in P1
    gemm_bt<<<g45, 256, 0, stream>>>(hprev_bf, 256, Bhht, b_hh, gh, 768, N_NODES, 256, 0);

    gru_kernel<<<(N_NODES*HIDF+255)/256, 256, 0, stream>>>(gi, gh, hprev, (float*)d_out);
}

// Round 10
// 459.800 us; speedup vs baseline: 1.3682x; 1.0888x over previous
//
#include <hip/hip_runtime.h>
#include <hip/hip_bf16.h>
#include <stdint.h>

#define N_NODES 20000
#define E_EDGES 320000
#define IN_F    128
#define HIDF    256
#define R_REL   4
#define NRKEYS  (N_NODES*R_REL)   // 80000
#define SCAN_BLOCKS 80            // 80*1024 = 81920 >= NRKEYS

typedef __attribute__((ext_vector_type(8))) short  short8;
typedef __attribute__((ext_vector_type(4))) float  floatx4;

__device__ __forceinline__ float bf2f(__hip_bfloat16 v){ return __bfloat162float(v); }
__device__ __forceinline__ __hip_bfloat16 f2bf(float v){ return __float2bfloat16(v); }
__device__ __forceinline__ float bfbits2f(unsigned short u){ return __uint_as_float(((unsigned)u)<<16); }
__device__ __forceinline__ unsigned short f2bfbits(float v){
    __hip_bfloat16 h = __float2bfloat16(v);
    return *(unsigned short*)&h;
}
__device__ __forceinline__ unsigned pack_bf2(float a, float b){
    return (unsigned)f2bfbits(a) | ((unsigned)f2bfbits(b) << 16);
}

// ---------------- CSR build ----------------
__global__ void count_kernel(const int* __restrict__ ei, const int* __restrict__ et,
                             int* __restrict__ cnt)
{
    int e = blockIdx.x*256 + threadIdx.x;
    if (e >= E_EDGES) return;
    int dst = ei[E_EDGES + e];
    atomicAdd(&cnt[dst*R_REL + et[e]], 1);
}

// 3-phase parallel exclusive scan over cnt[NRKEYS] -> row_ptr, cursor
__global__ __launch_bounds__(1024) void scan_reduce_kernel(const int* __restrict__ cnt,
                                                           int* __restrict__ blocksum)
{
    int ix = blockIdx.x*1024 + threadIdx.x;
    int v = (ix < NRKEYS) ? cnt[ix] : 0;
    #pragma unroll
    for (int o=32;o>0;o>>=1) v += __shfl_xor(v, o, 64);
    __shared__ int wsum[16];
    int wave = threadIdx.x >> 6, lane = threadIdx.x & 63;
    if (lane == 0) wsum[wave] = v;
    __syncthreads();
    if (threadIdx.x == 0) {
        int s = 0;
        #pragma unroll
        for (int w=0;w<16;w++) s += wsum[w];
        blocksum[blockIdx.x] = s;
    }
}

__global__ __launch_bounds__(128) void scan_sums_kernel(const int* __restrict__ blocksum,
                                                        int* __restrict__ blockoff)
{
    __shared__ int s[128];
    int t = threadIdx.x;
    int v = (t < SCAN_BLOCKS) ? blocksum[t] : 0;
    s[t] = v; __syncthreads();
    for (int off=1; off<128; off<<=1) {
        int u = (t>=off) ? s[t-off] : 0;
        __syncthreads();
        s[t] += u;
        __syncthreads();
    }
    if (t < SCAN_BLOCKS) blockoff[t] = s[t] - v;   // exclusive
}

__global__ __launch_bounds__(1024) void scan_apply_kernel(const int* __restrict__ cnt,
                                                          const int* __restrict__ blockoff,
                                                          int* __restrict__ row_ptr,
                                                          int* __restrict__ cursor)
{
    __shared__ int s[1024];
    int t = threadIdx.x;
    int ix = blockIdx.x*1024 + t;
    int v = (ix < NRKEYS) ? cnt[ix] : 0;
    s[t] = v; __syncthreads();
    for (int off=1; off<1024; off<<=1) {
        int u = (t>=off) ? s[t-off] : 0;
        __syncthreads();
        s[t] += u;
        __syncthreads();
    }
    if (ix < NRKEYS) {
        int excl = blockoff[blockIdx.x] + s[t] - v;
        row_ptr[ix] = excl;
        cursor[ix]  = excl;
        if (ix == NRKEYS-1) row_ptr[NRKEYS] = excl + v;
    }
}

__global__ void fill_kernel(const int* __restrict__ ei, const int* __restrict__ et,
                            int* __restrict__ cursor, int* __restrict__ csr_src)
{
    int e = blockIdx.x*256 + threadIdx.x;
    if (e >= E_EDGES) return;
    int src = ei[e];
    int dst = ei[E_EDGES + e];
    int key = dst*R_REL + et[e];
    int pos = atomicAdd(&cursor[key], 1);
    csr_src[pos] = src;
}

// ---------------- weight prep: fp32 sources -> bf16 B^T = [Nout][K] ----------------
__global__ void make_b1t(const float* __restrict__ root1,
                         const float* __restrict__ W1,
                         __hip_bfloat16* __restrict__ B1t)
{
    int idx = blockIdx.x*256 + threadIdx.x;         // n*640 + k
    if (idx >= 256*640) return;
    int n = idx / 640, k = idx % 640;
    float v;
    if (k < 128) v = root1[k*256 + n];
    else         v = W1[(k-128)*256 + n];           // W1 contiguous [R*128][256]
    B1t[idx] = f2bf(v);
}

__global__ void make_b2t(const float* __restrict__ root2,
                         const float* __restrict__ W2,
                         __hip_bfloat16* __restrict__ B2t)
{
    int idx = blockIdx.x*256 + threadIdx.x;         // n*1280 + k
    if (idx >= 256*1280) return;
    int n = idx / 1280, k = idx % 1280;
    float v;
    if (k < 256) v = root2[k*256 + n];
    else         v = W2[(k-256)*256 + n];           // W2 contiguous [R*256][256]
    B2t[idx] = f2bf(v);
}

__global__ void make_b3t(const float* __restrict__ Wq, const float* __restrict__ Wk,
                         const float* __restrict__ Wv, const float* __restrict__ Wsk,
                         const float* __restrict__ bq, const float* __restrict__ bk,
                         const float* __restrict__ bv, const float* __restrict__ bsk,
                         __hip_bfloat16* __restrict__ B3t, float* __restrict__ bias3)
{
    int idx = blockIdx.x*256 + threadIdx.x;         // n*256 + k, n<1024
    if (idx >= 1024*256) return;
    int n = idx / 256, k = idx % 256;
    int g = n >> 8, nn = n & 255;
    const float* W = (g==0)?Wq:(g==1)?Wk:(g==2)?Wv:Wsk;
    B3t[idx] = f2bf(W[k*256 + nn]);
    if (k == 0) {
        const float* B = (g==0)?bq:(g==1)?bk:(g==2)?bv:bsk;
        bias3[n] = B[nn];
    }
}

// generic fp32 -> bf16 elementwise convert (layout-preserving)
__global__ void cvt_f32_bf16(const float* __restrict__ in, __hip_bfloat16* __restrict__ out, int n)
{
    int i = blockIdx.x*256 + threadIdx.x;
    if (i < n) out[i] = f2bf(in[i]);
}

// ---------------- RGCN aggregation: one WAVE per (node,rel) key, unroll-4 ILP ----------------
// agg1: x fp32 [N,128]; lane covers dims 2*lane..2*lane+1 (float2, 8 B)
__global__ __launch_bounds__(256) void agg1_kernel(const float* __restrict__ x,
                                                   const int* __restrict__ row_ptr,
                                                   const int* __restrict__ csr_src,
                                                   __hip_bfloat16* __restrict__ A1)
{
    int b = blockIdx.x*4 + (threadIdx.x >> 6);   // key = i*4 + r
    int lane = threadIdx.x & 63;
    int i = b >> 2, r = b & 3;
    int e0 = row_ptr[b], e1 = row_ptr[b+1];
    float sx0=0.f,sy0=0.f, sx1=0.f,sy1=0.f, sx2=0.f,sy2=0.f, sx3=0.f,sy3=0.f;
    int e = e0;
    for (; e+4 <= e1; e += 4) {
        int i0=csr_src[e], i1=csr_src[e+1], i2=csr_src[e+2], i3=csr_src[e+3];
        float2 v0 = *(const float2*)(x + (size_t)i0*IN_F + lane*2);
        float2 v1 = *(const float2*)(x + (size_t)i1*IN_F + lane*2);
        float2 v2 = *(const float2*)(x + (size_t)i2*IN_F + lane*2);
        float2 v3 = *(const float2*)(x + (size_t)i3*IN_F + lane*2);
        sx0+=v0.x; sy0+=v0.y; sx1+=v1.x; sy1+=v1.y;
        sx2+=v2.x; sy2+=v2.y; sx3+=v3.x; sy3+=v3.y;
    }
    for (; e < e1; e++) {
        int i0 = csr_src[e];
        float2 v = *(const float2*)(x + (size_t)i0*IN_F + lane*2);
        sx0+=v.x; sy0+=v.y;
    }
    float sx = (sx0+sx1)+(sx2+sx3);
    float sy = (sy0+sy1)+(sy2+sy3);
    float inv = (e1>e0) ? 1.f/(float)(e1-e0) : 0.f;
    *(unsigned*)(A1 + (size_t)i*640 + 128 + r*128 + lane*2) = pack_bf2(sx*inv, sy*inv);
    if (r == 0) {
        float2 v = *(const float2*)(x + (size_t)i*IN_F + lane*2);
        *(unsigned*)(A1 + (size_t)i*640 + lane*2) = pack_bf2(v.x, v.y);
    }
}

// agg2: h1 bf16 in A2 cols 0..255 (ld 1280); lane covers dims 4*lane..4*lane+3 (ushort4, 8 B)
__global__ __launch_bounds__(256) void agg2_kernel(const int* __restrict__ row_ptr,
                                                   const int* __restrict__ csr_src,
                                                   __hip_bfloat16* __restrict__ A2)
{
    int b = blockIdx.x*4 + (threadIdx.x >> 6);
    int lane = threadIdx.x & 63;
    int i = b >> 2, r = b & 3;
    int e0 = row_ptr[b], e1 = row_ptr[b+1];
    float a0=0.f,a1=0.f,a2=0.f,a3=0.f;
    float b0=0.f,b1=0.f,b2=0.f,b3=0.f;
    float c0=0.f,c1=0.f,c2=0.f,c3=0.f;
    float d0=0.f,d1=0.f,d2=0.f,d3=0.f;
    int e = e0;
    for (; e+4 <= e1; e += 4) {
        int i0=csr_src[e], i1=csr_src[e+1], i2=csr_src[e+2], i3=csr_src[e+3];
        ushort4 u0 = *(const ushort4*)(A2 + (size_t)i0*1280 + lane*4);
        ushort4 u1 = *(const ushort4*)(A2 + (size_t)i1*1280 + lane*4);
        ushort4 u2 = *(const ushort4*)(A2 + (size_t)i2*1280 + lane*4);
        ushort4 u3 = *(const ushort4*)(A2 + (size_t)i3*1280 + lane*4);
        a0+=bfbits2f(u0.x); a1+=bfbits2f(u0.y); a2+=bfbits2f(u0.z); a3+=bfbits2f(u0.w);
        b0+=bfbits2f(u1.x); b1+=bfbits2f(u1.y); b2+=bfbits2f(u1.z); b3+=bfbits2f(u1.w);
        c0+=bfbits2f(u2.x); c1+=bfbits2f(u2.y); c2+=bfbits2f(u2.z); c3+=bfbits2f(u2.w);
        d0+=bfbits2f(u3.x); d1+=bfbits2f(u3.y); d2+=bfbits2f(u3.z); d3+=bfbits2f(u3.w);
    }
    for (; e < e1; e++) {
        int i0 = csr_src[e];
        ushort4 u = *(const ushort4*)(A2 + (size_t)i0*1280 + lane*4);
        a0+=bfbits2f(u.x); a1+=bfbits2f(u.y); a2+=bfbits2f(u.z); a3+=bfbits2f(u.w);
    }
    float s0=(a0+b0)+(c0+d0), s1=(a1+b1)+(c1+d1), s2=(a2+b2)+(c2+d2), s3=(a3+b3)+(c3+d3);
    float inv = (e1>e0) ? 1.f/(float)(e1-e0) : 0.f;
    uint2 w;
    w.x = pack_bf2(s0*inv, s1*inv);
    w.y = pack_bf2(s2*inv, s3*inv);
    *(uint2*)(A2 + (size_t)i*1280 + 256 + r*256 + lane*4) = w;
}

// ---------------- MFMA GEMM: C[M x Nout] = act(A[M x K] * Bt[Nout x K]^T + bias) ----------------
__device__ __forceinline__ void gemm_bt_body(const __hip_bfloat16* __restrict__ A, int lda,
                                             const __hip_bfloat16* __restrict__ Bt,
                                             const float* __restrict__ bias,
                                             __hip_bfloat16* __restrict__ C, int ldc,
                                             int M, int K, int relu,
                                             int tile_m, int tile_n,
                                             __hip_bfloat16* lds_a, __hip_bfloat16* lds_b)
{
    const int tid    = threadIdx.x;
    const int wave   = tid >> 6;
    const int lane   = tid & 63;
    const int wm = wave >> 1, wn = wave & 1;     // 2x2 wave grid: 64x64 each
    const int fm = lane & 15;
    const int q  = lane >> 4;

    floatx4 acc[4][4];
    #pragma unroll
    for (int i=0;i<4;i++)
        #pragma unroll
        for (int j=0;j<4;j++) acc[i][j] = (floatx4){0.f,0.f,0.f,0.f};

    const int srow   = tid >> 2;
    const int schunk = (tid & 3) * 8;

    for (int k0 = 0; k0 < K; k0 += 32) {
        __syncthreads();
        #pragma unroll
        for (int p=0;p<2;p++) {
            int row = p*64 + srow;
            int ga  = min(tile_m + row, M-1);
            uint4 v = *(const uint4*)(A + (size_t)ga*lda + k0 + schunk);
            *(uint4*)(&lds_a[row*32 + schunk]) = v;
        }
        #pragma unroll
        for (int p=0;p<2;p++) {
            int row = p*64 + srow;
            uint4 v = *(const uint4*)(Bt + (size_t)(tile_n + row)*K + k0 + schunk);
            *(uint4*)(&lds_b[row*32 + schunk]) = v;
        }
        __syncthreads();

        short8 afr[4], bfr[4];
        #pragma unroll
        for (int i=0;i<4;i++) {
            afr[i] = *(const short8*)(&lds_a[(wm*64 + i*16 + fm)*32 + q*8]);
            bfr[i] = *(const short8*)(&lds_b[(wn*64 + i*16 + fm)*32 + q*8]);
        }
        #pragma unroll
        for (int i=0;i<4;i++)
            #pragma unroll
            for (int j=0;j<4;j++)
                acc[i][j] = __builtin_amdgcn_mfma_f32_16x16x32_bf16(afr[i], bfr[j], acc[i][j], 0,0,0);
    }

    const int crow_base = tile_m + wm*64;
    const int ccol_base = tile_n + wn*64;
    #pragma unroll
    for (int i=0;i<4;i++) {
        #pragma unroll
        for (int j=0;j<4;j++) {
            int c  = ccol_base + j*16 + fm;
            float bb = bias[c];
            #pragma unroll
            for (int rg=0; rg<4; rg++) {
                int r = crow_base + i*16 + q*4 + rg;
                if (r < M) {
                    float v = acc[i][j][rg] + bb;
                    if (relu) v = fmaxf(v, 0.f);
                    C[(size_t)r*ldc + c] = f2bf(v);
                }
            }
        }
    }
}

__global__ __launch_bounds__(256) void gemm_bt(const __hip_bfloat16* __restrict__ A, int lda,
                                               const __hip_bfloat16* __restrict__ Bt,
                                               const float* __restrict__ bias,
                                               __hip_bfloat16* __restrict__ C, int ldc,
                                               int M, int K, int relu)
{
    __shared__ __align__(16) __hip_bfloat16 lds_a[128*32];
    __shared__ __align__(16) __hip_bfloat16 lds_b[128*32];
    gemm_bt_body(A, lda, Bt, bias, C, ldc, M, K, relu,
                 blockIdx.x*128, blockIdx.y*128, lds_a, lds_b);
}

// two independent GEMMs (same M=N_NODES, K=256, N=768) in one dispatch:
// blockIdx.y in [0,6) -> problem 0 (A0->C0), [6,12) -> problem 1 (A1->C1)
__global__ __launch_bounds__(256) void gemm_bt_dual(const __hip_bfloat16* __restrict__ A0,
                                                    const __hip_bfloat16* __restrict__ A1,
                                                    const __hip_bfloat16* __restrict__ Bt0,
                                                    const __hip_bfloat16* __restrict__ Bt1,
                                                    const float* __restrict__ bias0,
                                                    const float* __restrict__ bias1,
                                                    __hip_bfloat16* __restrict__ C0,
                                                    __hip_bfloat16* __restrict__ C1)
{
    __shared__ __align__(16) __hip_bfloat16 lds_a[128*32];
    __shared__ __align__(16) __hip_bfloat16 lds_b[128*32];
    int which = blockIdx.y >= 6;
    int ty    = which ? (blockIdx.y - 6) : blockIdx.y;
    gemm_bt_body(which ? A1 : A0, 256,
                 which ? Bt1 : Bt0,
                 which ? bias1 : bias0,
                 which ? C1 : C0, 768,
                 N_NODES, 256, 0,
                 blockIdx.x*128, ty*128, lds_a, lds_b);
}

// ---------------- attention scores: ONE WAVE PER NODE ----------------
// q[dst] loaded once into registers; loop node's edges with unroll-2 ILP on
// the k-gather. lane = h*16 + d4 covers dims lane*4..lane*4+3; 16-lane group
// reduce -> head dot. score[h][p] planes, CSR-position-indexed.
__global__ __launch_bounds__(256) void score_kernel(const __hip_bfloat16* __restrict__ qkvs,
                                                    const int* __restrict__ row_ptr,
                                                    const int* __restrict__ csr_src,
                                                    float* __restrict__ score)
{
    int i = blockIdx.x*4 + (threadIdx.x >> 6);
    int lane = threadIdx.x & 63;
    int h = lane >> 4, d4 = lane & 15;
    int e0 = row_ptr[i*R_REL], e1 = row_ptr[i*R_REL + R_REL];
    ushort4 qv = *(const ushort4*)(qkvs + (size_t)i*1024 + lane*4);
    float qx=bfbits2f(qv.x), qy=bfbits2f(qv.y), qz=bfbits2f(qv.z), qw=bfbits2f(qv.w);
    float* sp = score + (size_t)h*E_EDGES;
    int j = e0;
    for (; j+2 <= e1; j += 2) {
        int s0 = csr_src[j], s1 = csr_src[j+1];
        ushort4 k0 = *(const ushort4*)(qkvs + (size_t)s0*1024 + 256 + lane*4);
        ushort4 k1 = *(const ushort4*)(qkvs + (size_t)s1*1024 + 256 + lane*4);
        float d0 = qx*bfbits2f(k0.x)+qy*bfbits2f(k0.y)+qz*bfbits2f(k0.z)+qw*bfbits2f(k0.w);
        float d1 = qx*bfbits2f(k1.x)+qy*bfbits2f(k1.y)+qz*bfbits2f(k1.z)+qw*bfbits2f(k1.w);
        #pragma unroll
        for (int o=1;o<16;o<<=1){ d0 += __shfl_xor(d0,o,64); d1 += __shfl_xor(d1,o,64); }
        if (d4 == 0) { sp[j] = d0*0.125f; sp[j+1] = d1*0.125f; }
    }
    for (; j < e1; j++) {
        int s0 = csr_src[j];
        ushort4 k0 = *(const ushort4*)(qkvs + (size_t)s0*1024 + 256 + lane*4);
        float d0 = qx*bfbits2f(k0.x)+qy*bfbits2f(k0.y)+qz*bfbits2f(k0.z)+qw*bfbits2f(k0.w);
        #pragma unroll
        for (int o=1;o<16;o<<=1) d0 += __shfl_xor(d0,o,64);
        if (d4 == 0) sp[j] = d0*0.125f;
    }
}

// ---------------- attention aggregate: ONE WAVE PER NODE, all 4 heads ----------------
__global__ __launch_bounds__(256) void attn_agg_kernel(const __hip_bfloat16* __restrict__ qkvs,
                                                       const float* __restrict__ score,
                                                       const int* __restrict__ row_ptr,
                                                       const int* __restrict__ csr_src,
                                                       __hip_bfloat16* __restrict__ hatt)
{
    int i = blockIdx.x*4 + (threadIdx.x >> 6);   // node (4 nodes per block)
    int lane = threadIdx.x & 63;
    int h  = lane >> 4;
    int d4 = lane & 15;
    int e0 = row_ptr[i*R_REL], e1 = row_ptr[i*R_REL + R_REL];
    int deg = e1 - e0;
    const float* sp = score + (size_t)h*E_EDGES + e0;

    // pass 1: per-head max
    float m = -1e30f;
    for (int j = d4; j < deg; j += 16) m = fmaxf(m, sp[j]);
    #pragma unroll
    for (int o=1;o<16;o<<=1) m = fmaxf(m, __shfl_xor(m, o, 64));

    // pass 2: per-head denom
    float ssum = 0.f;
    for (int j = d4; j < deg; j += 16) ssum += __expf(sp[j] - m);
    #pragma unroll
    for (int o=1;o<16;o<<=1) ssum += __shfl_xor(ssum, o, 64);
    float inv = 1.f / fmaxf(ssum, 1e-16f);

    // pass 3: all lanes walk all edges (unroll 4), no cross-lane reduction
    float ax=0.f, ay=0.f, az=0.f, aw=0.f;
    int j = 0;
    for (; j+4 <= deg; j += 4) {
        int s0=csr_src[e0+j], s1=csr_src[e0+j+1], s2=csr_src[e0+j+2], s3=csr_src[e0+j+3];
        float w0 = __expf(sp[j]   - m) * inv;
        float w1 = __expf(sp[j+1] - m) * inv;
        float w2 = __expf(sp[j+2] - m) * inv;
        float w3 = __expf(sp[j+3] - m) * inv;
        ushort4 u0 = *(const ushort4*)(qkvs + (size_t)s0*1024 + 512 + lane*4);
        ushort4 u1 = *(const ushort4*)(qkvs + (size_t)s1*1024 + 512 + lane*4);
        ushort4 u2 = *(const ushort4*)(qkvs + (size_t)s2*1024 + 512 + lane*4);
        ushort4 u3 = *(const ushort4*)(qkvs + (size_t)s3*1024 + 512 + lane*4);
        ax += w0*bfbits2f(u0.x) + w1*bfbits2f(u1.x) + w2*bfbits2f(u2.x) + w3*bfbits2f(u3.x);
        ay += w0*bfbits2f(u0.y) + w1*bfbits2f(u1.y) + w2*bfbits2f(u2.y) + w3*bfbits2f(u3.y);
        az += w0*bfbits2f(u0.z) + w1*bfbits2f(u1.z) + w2*bfbits2f(u2.z) + w3*bfbits2f(u3.z);
        aw += w0*bfbits2f(u0.w) + w1*bfbits2f(u1.w) + w2*bfbits2f(u2.w) + w3*bfbits2f(u3.w);
    }
    for (; j < deg; j++) {
        int s = csr_src[e0+j];
        float w = __expf(sp[j] - m) * inv;
        ushort4 u = *(const ushort4*)(qkvs + (size_t)s*1024 + 512 + lane*4);
        ax += w*bfbits2f(u.x); ay += w*bfbits2f(u.y);
        az += w*bfbits2f(u.z); aw += w*bfbits2f(u.w);
    }
    ushort4 sk = *(const ushort4*)(qkvs + (size_t)i*1024 + 768 + lane*4);
    uint2 w;
    w.x = pack_bf2(ax + bfbits2f(sk.x), ay + bfbits2f(sk.y));
    w.y = pack_bf2(az + bfbits2f(sk.z), aw + bfbits2f(sk.w));
    *(uint2*)(hatt + (size_t)i*256 + lane*4) = w;
}

// ---------------- GRU elementwise (bf16 gates, fp32 math, fp32 out) ----------------
__global__ void gru_kernel(const __hip_bfloat16* __restrict__ gi,
                           const __hip_bfloat16* __restrict__ gh,
                           const float* __restrict__ hprev,
                           float* __restrict__ out)
{
    int idx = blockIdx.x*256 + threadIdx.x;
    if (idx >= N_NODES*HIDF) return;
    int i = idx / HIDF, c = idx % HIDF;
    size_t gb = (size_t)i*768;
    float ir = bf2f(gi[gb + c]), iz = bf2f(gi[gb + 256 + c]), in = bf2f(gi[gb + 512 + c]);
    float hr = bf2f(gh[gb + c]), hz = bf2f(gh[gb + 256 + c]), hn = bf2f(gh[gb + 512 + c]);
    float r = 1.f/(1.f + __expf(-(ir+hr)));
    float z = 1.f/(1.f + __expf(-(iz+hz)));
    float n = tanhf(in + r*hn);
    float h = hprev[idx];
    out[idx] = (1.f - z)*n + z*h;
}

// ---------------- launch ----------------
// Inputs fp32 (verified round 3); bf16 internally for MFMA. Workspace ~107 MB:
//   P1 (25.6 MB):  A1 -> h2 -> hatt
//   P2 (61.4 MB):  A2 -> qkvs -> (gi | gh)   (gi at 0, gh at +N*768 elements)
// gemm4+5 merged (gemm_bt_dual): reads hatt (P1) + hprev_bf, writes gi+gh (P2
// over dead qkvs) -- no ordering hazard.
extern "C" void kernel_launch(void* const* d_in, const int* in_sizes, int n_in,
                              void* d_out, int out_size, void* d_ws, size_t ws_size,
                              hipStream_t stream)
{
    const float* x       = (const float*)d_in[0];
    const int* edge_index= (const int*)d_in[1];
    const int* edge_type = (const int*)d_in[2];
    const float* hprev   = (const float*)d_in[3];
    const float* W1      = (const float*)d_in[4];
    const float* root1   = (const float*)d_in[5];
    const float* b1      = (const float*)d_in[6];
    const float* W2      = (const float*)d_in[7];
    const float* root2   = (const float*)d_in[8];
    const float* b2      = (const float*)d_in[9];
    const float* Wq      = (const float*)d_in[10];
    const float* bq      = (const float*)d_in[11];
    const float* Wk      = (const float*)d_in[12];
    const float* bk      = (const float*)d_in[13];
    const float* Wv      = (const float*)d_in[14];
    const float* bv      = (const float*)d_in[15];
    const float* Wskip   = (const float*)d_in[16];
    const float* bskip   = (const float*)d_in[17];
    const float* W_ih    = (const float*)d_in[18];
    const float* b_ih    = (const float*)d_in[19];
    const float* W_hh    = (const float*)d_in[20];
    const float* b_hh    = (const float*)d_in[21];

    char* ws = (char*)d_ws;
    size_t off = 0;
    auto take = [&](size_t bytes)->char* {
        char* p = ws + off;
        off = (off + bytes + 255) & ~(size_t)255;
        return p;
    };
    int* cnt        = (int*)take((size_t)NRKEYS*4);
    int* row_ptr    = (int*)take((size_t)(NRKEYS+1)*4);
    int* cursor     = (int*)take((size_t)NRKEYS*4);
    int* csr_src    = (int*)take((size_t)E_EDGES*4);
    int* blocksum   = (int*)take((size_t)SCAN_BLOCKS*4);
    int* blockoff   = (int*)take((size_t)(SCAN_BLOCKS+1)*4);
    float* score    = (float*)take((size_t)R_REL*E_EDGES*4);   // [HEADS][E], CSR-position-indexed
    __hip_bfloat16* B1t   = (__hip_bfloat16*)take((size_t)256*640*2);
    __hip_bfloat16* B2t   = (__hip_bfloat16*)take((size_t)256*1280*2);
    __hip_bfloat16* B3t   = (__hip_bfloat16*)take((size_t)1024*256*2);
    __hip_bfloat16* Biht  = (__hip_bfloat16*)take((size_t)768*256*2);
    __hip_bfloat16* Bhht  = (__hip_bfloat16*)take((size_t)768*256*2);
    float*          bias3 = (float*)take((size_t)1024*4);
    __hip_bfloat16* hprev_bf = (__hip_bfloat16*)take((size_t)N_NODES*256*2);
    // P1: max(A1 N*640, h2 N*256, hatt N*256) bf16
    char* P1 = take((size_t)N_NODES*640*2);
    // P2: max(A2 N*1280, qkvs N*1024, gi+gh N*1536) bf16
    char* P2 = take((size_t)N_NODES*1536*2);

    __hip_bfloat16* A1   = (__hip_bfloat16*)P1;   // [N,640]  dead after gemm1
    __hip_bfloat16* h2   = (__hip_bfloat16*)P1;   // [N,256]  dead after gemm3
    __hip_bfloat16* hatt = (__hip_bfloat16*)P1;   // [N,256]  read by gemm45
    __hip_bfloat16* A2   = (__hip_bfloat16*)P2;   // [N,1280] dead after gemm2
    __hip_bfloat16* qkvs = (__hip_bfloat16*)P2;   // [N,1024] dead after attn_agg
    __hip_bfloat16* gi   = (__hip_bfloat16*)P2;                          // [N,768]
    __hip_bfloat16* gh   = (__hip_bfloat16*)(P2 + (size_t)N_NODES*768*2); // [N,768]

    hipMemsetAsync(cnt, 0, (size_t)NRKEYS*4, stream);
    count_kernel<<<(E_EDGES+255)/256, 256, 0, stream>>>(edge_index, edge_type, cnt);
    scan_reduce_kernel<<<SCAN_BLOCKS, 1024, 0, stream>>>(cnt, blocksum);
    scan_sums_kernel<<<1, 128, 0, stream>>>(blocksum, blockoff);
    scan_apply_kernel<<<SCAN_BLOCKS, 1024, 0, stream>>>(cnt, blockoff, row_ptr, cursor);
    fill_kernel<<<(E_EDGES+255)/256, 256, 0, stream>>>(edge_index, edge_type, cursor, csr_src);

    make_b1t<<<(256*640+255)/256, 256, 0, stream>>>(root1, W1, B1t);
    make_b2t<<<(256*1280+255)/256, 256, 0, stream>>>(root2, W2, B2t);
    make_b3t<<<(1024*256+255)/256, 256, 0, stream>>>(Wq, Wk, Wv, Wskip, bq, bk, bv, bskip, B3t, bias3);
    cvt_f32_bf16<<<(768*256+255)/256, 256, 0, stream>>>(W_ih, Biht, 768*256);
    cvt_f32_bf16<<<(768*256+255)/256, 256, 0, stream>>>(W_hh, Bhht, 768*256);
    cvt_f32_bf16<<<(N_NODES*256+255)/256, 256, 0, stream>>>(hprev, hprev_bf, N_NODES*256);

    // one wave per (node,rel) key; block covers node's 4 rels
    agg1_kernel<<<NRKEYS/4, 256, 0, stream>>>(x, row_ptr, csr_src, A1);

    dim3 g12(157, 2);
    // h1 = relu(A1 * B1) written into A2 cols 0..255 (ldc=1280)
    gemm_bt<<<g12, 256, 0, stream>>>(A1, 640, B1t, b1, A2, 1280, N_NODES, 640, 1);

    agg2_kernel<<<NRKEYS/4, 256, 0, stream>>>(row_ptr, csr_src, A2);

    // h2 overwrites A1 (dead) in P1
    gemm_bt<<<g12, 256, 0, stream>>>(A2, 1280, B2t, b2, h2, 256, N_NODES, 1280, 1);

    // qkvs overwrites A2 (dead) in P2
    dim3 g3(157, 8);
    gemm_bt<<<g3, 256, 0, stream>>>(h2, 256, B3t, bias3, qkvs, 1024, N_NODES, 256, 0);

    // attention: one-wave-per-node scores, then one-wave-per-node aggregate
    score_kernel<<<N_NODES/4, 256, 0, stream>>>(qkvs, row_ptr, csr_src, score);
    attn_agg_kernel<<<N_NODES/4, 256, 0, stream>>>(qkvs, score, row_ptr, csr_src, hatt);

    // fused GRU gate GEMMs: gi = hatt*W_ih^T + b_ih ; gh = hprev*W_hh^T + b_hh
    dim3 g45(157, 12);
    gemm_bt_dual<<<g45, 256, 0, stream>>>(hatt, hprev_bf, Biht, Bhht, b_ih, b_hh, gi, gh);

    gru_kernel<<<(N_NODES*HIDF+255)/256, 256, 0, stream>>>(gi, gh, hprev, (float*)d_out);
}

// Round 11
// 449.831 us; speedup vs baseline: 1.3985x; 1.0222x over previous
//
#include <hip/hip_runtime.h>
#include <hip/hip_bf16.h>
#include <stdint.h>

#define N_NODES 20000
#define E_EDGES 320000
#define IN_F    128
#define HIDF    256
#define R_REL   4
#define NRKEYS  (N_NODES*R_REL)   // 80000
#define SCAN_BLOCKS 80            // 80*1024 = 81920 >= NRKEYS
#define LDSP    40                // padded LDS row stride (elements): stride-20
                                  // dwords mod 32 banks -> 2-way (free) vs 8-way at 32

typedef __attribute__((ext_vector_type(8))) short  short8;
typedef __attribute__((ext_vector_type(4))) float  floatx4;

__device__ __forceinline__ float bf2f(__hip_bfloat16 v){ return __bfloat162float(v); }
__device__ __forceinline__ __hip_bfloat16 f2bf(float v){ return __float2bfloat16(v); }
__device__ __forceinline__ float bfbits2f(unsigned short u){ return __uint_as_float(((unsigned)u)<<16); }
__device__ __forceinline__ unsigned short f2bfbits(float v){
    __hip_bfloat16 h = __float2bfloat16(v);
    return *(unsigned short*)&h;
}
__device__ __forceinline__ unsigned pack_bf2(float a, float b){
    return (unsigned)f2bfbits(a) | ((unsigned)f2bfbits(b) << 16);
}

// ---------------- CSR build ----------------
__global__ void count_kernel(const int* __restrict__ ei, const int* __restrict__ et,
                             int* __restrict__ cnt)
{
    int e = blockIdx.x*256 + threadIdx.x;
    if (e >= E_EDGES) return;
    int dst = ei[E_EDGES + e];
    atomicAdd(&cnt[dst*R_REL + et[e]], 1);
}

// 3-phase parallel exclusive scan over cnt[NRKEYS] -> row_ptr, cursor
__global__ __launch_bounds__(1024) void scan_reduce_kernel(const int* __restrict__ cnt,
                                                           int* __restrict__ blocksum)
{
    int ix = blockIdx.x*1024 + threadIdx.x;
    int v = (ix < NRKEYS) ? cnt[ix] : 0;
    #pragma unroll
    for (int o=32;o>0;o>>=1) v += __shfl_xor(v, o, 64);
    __shared__ int wsum[16];
    int wave = threadIdx.x >> 6, lane = threadIdx.x & 63;
    if (lane == 0) wsum[wave] = v;
    __syncthreads();
    if (threadIdx.x == 0) {
        int s = 0;
        #pragma unroll
        for (int w=0;w<16;w++) s += wsum[w];
        blocksum[blockIdx.x] = s;
    }
}

__global__ __launch_bounds__(128) void scan_sums_kernel(const int* __restrict__ blocksum,
                                                        int* __restrict__ blockoff)
{
    __shared__ int s[128];
    int t = threadIdx.x;
    int v = (t < SCAN_BLOCKS) ? blocksum[t] : 0;
    s[t] = v; __syncthreads();
    for (int off=1; off<128; off<<=1) {
        int u = (t>=off) ? s[t-off] : 0;
        __syncthreads();
        s[t] += u;
        __syncthreads();
    }
    if (t < SCAN_BLOCKS) blockoff[t] = s[t] - v;   // exclusive
}

__global__ __launch_bounds__(1024) void scan_apply_kernel(const int* __restrict__ cnt,
                                                          const int* __restrict__ blockoff,
                                                          int* __restrict__ row_ptr,
                                                          int* __restrict__ cursor)
{
    __shared__ int s[1024];
    int t = threadIdx.x;
    int ix = blockIdx.x*1024 + t;
    int v = (ix < NRKEYS) ? cnt[ix] : 0;
    s[t] = v; __syncthreads();
    for (int off=1; off<1024; off<<=1) {
        int u = (t>=off) ? s[t-off] : 0;
        __syncthreads();
        s[t] += u;
        __syncthreads();
    }
    if (ix < NRKEYS) {
        int excl = blockoff[blockIdx.x] + s[t] - v;
        row_ptr[ix] = excl;
        cursor[ix]  = excl;
        if (ix == NRKEYS-1) row_ptr[NRKEYS] = excl + v;
    }
}

__global__ void fill_kernel(const int* __restrict__ ei, const int* __restrict__ et,
                            int* __restrict__ cursor, int* __restrict__ csr_src)
{
    int e = blockIdx.x*256 + threadIdx.x;
    if (e >= E_EDGES) return;
    int src = ei[e];
    int dst = ei[E_EDGES + e];
    int key = dst*R_REL + et[e];
    int pos = atomicAdd(&cursor[key], 1);
    csr_src[pos] = src;
}

// ---------------- weight prep: fp32 sources -> bf16 B^T = [Nout][K] ----------------
__global__ void make_b1t(const float* __restrict__ root1,
                         const float* __restrict__ W1,
                         __hip_bfloat16* __restrict__ B1t)
{
    int idx = blockIdx.x*256 + threadIdx.x;         // n*640 + k
    if (idx >= 256*640) return;
    int n = idx / 640, k = idx % 640;
    float v;
    if (k < 128) v = root1[k*256 + n];
    else         v = W1[(k-128)*256 + n];           // W1 contiguous [R*128][256]
    B1t[idx] = f2bf(v);
}

__global__ void make_b2t(const float* __restrict__ root2,
                         const float* __restrict__ W2,
                         __hip_bfloat16* __restrict__ B2t)
{
    int idx = blockIdx.x*256 + threadIdx.x;         // n*1280 + k
    if (idx >= 256*1280) return;
    int n = idx / 1280, k = idx % 1280;
    float v;
    if (k < 256) v = root2[k*256 + n];
    else         v = W2[(k-256)*256 + n];           // W2 contiguous [R*256][256]
    B2t[idx] = f2bf(v);
}

__global__ void make_b3t(const float* __restrict__ Wq, const float* __restrict__ Wk,
                         const float* __restrict__ Wv, const float* __restrict__ Wsk,
                         const float* __restrict__ bq, const float* __restrict__ bk,
                         const float* __restrict__ bv, const float* __restrict__ bsk,
                         __hip_bfloat16* __restrict__ B3t, float* __restrict__ bias3)
{
    int idx = blockIdx.x*256 + threadIdx.x;         // n*256 + k, n<1024
    if (idx >= 1024*256) return;
    int n = idx / 256, k = idx % 256;
    int g = n >> 8, nn = n & 255;
    const float* W = (g==0)?Wq:(g==1)?Wk:(g==2)?Wv:Wsk;
    B3t[idx] = f2bf(W[k*256 + nn]);
    if (k == 0) {
        const float* B = (g==0)?bq:(g==1)?bk:(g==2)?bv:bsk;
        bias3[n] = B[nn];
    }
}

// generic fp32 -> bf16 elementwise convert (layout-preserving)
__global__ void cvt_f32_bf16(const float* __restrict__ in, __hip_bfloat16* __restrict__ out, int n)
{
    int i = blockIdx.x*256 + threadIdx.x;
    if (i < n) out[i] = f2bf(in[i]);
}

// ---------------- RGCN aggregation: one WAVE per (node,rel) key, unroll-4 ILP ----------------
// agg1: x fp32 [N,128]; lane covers dims 2*lane..2*lane+1 (float2, 8 B)
__global__ __launch_bounds__(256) void agg1_kernel(const float* __restrict__ x,
                                                   const int* __restrict__ row_ptr,
                                                   const int* __restrict__ csr_src,
                                                   __hip_bfloat16* __restrict__ A1)
{
    int b = blockIdx.x*4 + (threadIdx.x >> 6);   // key = i*4 + r
    int lane = threadIdx.x & 63;
    int i = b >> 2, r = b & 3;
    int e0 = row_ptr[b], e1 = row_ptr[b+1];
    float sx0=0.f,sy0=0.f, sx1=0.f,sy1=0.f, sx2=0.f,sy2=0.f, sx3=0.f,sy3=0.f;
    int e = e0;
    for (; e+4 <= e1; e += 4) {
        int i0=csr_src[e], i1=csr_src[e+1], i2=csr_src[e+2], i3=csr_src[e+3];
        float2 v0 = *(const float2*)(x + (size_t)i0*IN_F + lane*2);
        float2 v1 = *(const float2*)(x + (size_t)i1*IN_F + lane*2);
        float2 v2 = *(const float2*)(x + (size_t)i2*IN_F + lane*2);
        float2 v3 = *(const float2*)(x + (size_t)i3*IN_F + lane*2);
        sx0+=v0.x; sy0+=v0.y; sx1+=v1.x; sy1+=v1.y;
        sx2+=v2.x; sy2+=v2.y; sx3+=v3.x; sy3+=v3.y;
    }
    for (; e < e1; e++) {
        int i0 = csr_src[e];
        float2 v = *(const float2*)(x + (size_t)i0*IN_F + lane*2);
        sx0+=v.x; sy0+=v.y;
    }
    float sx = (sx0+sx1)+(sx2+sx3);
    float sy = (sy0+sy1)+(sy2+sy3);
    float inv = (e1>e0) ? 1.f/(float)(e1-e0) : 0.f;
    *(unsigned*)(A1 + (size_t)i*640 + 128 + r*128 + lane*2) = pack_bf2(sx*inv, sy*inv);
    if (r == 0) {
        float2 v = *(const float2*)(x + (size_t)i*IN_F + lane*2);
        *(unsigned*)(A1 + (size_t)i*640 + lane*2) = pack_bf2(v.x, v.y);
    }
}

// agg2: h1 bf16 in A2 cols 0..255 (ld 1280); lane covers dims 4*lane..4*lane+3 (ushort4, 8 B)
__global__ __launch_bounds__(256) void agg2_kernel(const int* __restrict__ row_ptr,
                                                   const int* __restrict__ csr_src,
                                                   __hip_bfloat16* __restrict__ A2)
{
    int b = blockIdx.x*4 + (threadIdx.x >> 6);
    int lane = threadIdx.x & 63;
    int i = b >> 2, r = b & 3;
    int e0 = row_ptr[b], e1 = row_ptr[b+1];
    float a0=0.f,a1=0.f,a2=0.f,a3=0.f;
    float b0=0.f,b1=0.f,b2=0.f,b3=0.f;
    float c0=0.f,c1=0.f,c2=0.f,c3=0.f;
    float d0=0.f,d1=0.f,d2=0.f,d3=0.f;
    int e = e0;
    for (; e+4 <= e1; e += 4) {
        int i0=csr_src[e], i1=csr_src[e+1], i2=csr_src[e+2], i3=csr_src[e+3];
        ushort4 u0 = *(const ushort4*)(A2 + (size_t)i0*1280 + lane*4);
        ushort4 u1 = *(const ushort4*)(A2 + (size_t)i1*1280 + lane*4);
        ushort4 u2 = *(const ushort4*)(A2 + (size_t)i2*1280 + lane*4);
        ushort4 u3 = *(const ushort4*)(A2 + (size_t)i3*1280 + lane*4);
        a0+=bfbits2f(u0.x); a1+=bfbits2f(u0.y); a2+=bfbits2f(u0.z); a3+=bfbits2f(u0.w);
        b0+=bfbits2f(u1.x); b1+=bfbits2f(u1.y); b2+=bfbits2f(u1.z); b3+=bfbits2f(u1.w);
        c0+=bfbits2f(u2.x); c1+=bfbits2f(u2.y); c2+=bfbits2f(u2.z); c3+=bfbits2f(u2.w);
        d0+=bfbits2f(u3.x); d1+=bfbits2f(u3.y); d2+=bfbits2f(u3.z); d3+=bfbits2f(u3.w);
    }
    for (; e < e1; e++) {
        int i0 = csr_src[e];
        ushort4 u = *(const ushort4*)(A2 + (size_t)i0*1280 + lane*4);
        a0+=bfbits2f(u.x); a1+=bfbits2f(u.y); a2+=bfbits2f(u.z); a3+=bfbits2f(u.w);
    }
    float s0=(a0+b0)+(c0+d0), s1=(a1+b1)+(c1+d1), s2=(a2+b2)+(c2+d2), s3=(a3+b3)+(c3+d3);
    float inv = (e1>e0) ? 1.f/(float)(e1-e0) : 0.f;
    uint2 w;
    w.x = pack_bf2(s0*inv, s1*inv);
    w.y = pack_bf2(s2*inv, s3*inv);
    *(uint2*)(A2 + (size_t)i*1280 + 256 + r*256 + lane*4) = w;
}

// ---------------- MFMA GEMM: C[M x Nout] = act(A[M x K] * Bt[Nout x K]^T + bias) ----------------
// LDS rows padded to LDSP=40 elems (2-way bank aliasing, free) and the next
// K-tile's global loads are issued into registers BEFORE the MFMA burst so
// their latency hides behind compute (register-prefetch pipeline).
__device__ __forceinline__ void gemm_bt_body(const __hip_bfloat16* __restrict__ A, int lda,
                                             const __hip_bfloat16* __restrict__ Bt,
                                             const float* __restrict__ bias,
                                             __hip_bfloat16* __restrict__ C, int ldc,
                                             int M, int K, int relu,
                                             int tile_m, int tile_n,
                                             __hip_bfloat16* lds_a, __hip_bfloat16* lds_b)
{
    const int tid    = threadIdx.x;
    const int wave   = tid >> 6;
    const int lane   = tid & 63;
    const int wm = wave >> 1, wn = wave & 1;     // 2x2 wave grid: 64x64 each
    const int fm = lane & 15;
    const int q  = lane >> 4;

    floatx4 acc[4][4];
    #pragma unroll
    for (int i=0;i<4;i++)
        #pragma unroll
        for (int j=0;j<4;j++) acc[i][j] = (floatx4){0.f,0.f,0.f,0.f};

    const int srow   = tid >> 2;                 // 0..63
    const int schunk = (tid & 3) * 8;
    const int ga0 = min(tile_m + srow,      M-1);
    const int ga1 = min(tile_m + 64 + srow, M-1);
    const __hip_bfloat16* arow0 = A  + (size_t)ga0*lda + schunk;
    const __hip_bfloat16* arow1 = A  + (size_t)ga1*lda + schunk;
    const __hip_bfloat16* brow0 = Bt + (size_t)(tile_n + srow)*K      + schunk;
    const __hip_bfloat16* brow1 = Bt + (size_t)(tile_n + 64 + srow)*K + schunk;

    uint4 pa0 = *(const uint4*)(arow0);
    uint4 pa1 = *(const uint4*)(arow1);
    uint4 pb0 = *(const uint4*)(brow0);
    uint4 pb1 = *(const uint4*)(brow1);

    for (int k0 = 0; k0 < K; k0 += 32) {
        __syncthreads();
        *(uint4*)(&lds_a[srow*LDSP      + schunk]) = pa0;
        *(uint4*)(&lds_a[(64+srow)*LDSP + schunk]) = pa1;
        *(uint4*)(&lds_b[srow*LDSP      + schunk]) = pb0;
        *(uint4*)(&lds_b[(64+srow)*LDSP + schunk]) = pb1;
        __syncthreads();

        int kn = k0 + 32;
        if (kn < K) {                 // prefetch next tile; latency hides under MFMA
            pa0 = *(const uint4*)(arow0 + kn);
            pa1 = *(const uint4*)(arow1 + kn);
            pb0 = *(const uint4*)(brow0 + kn);
            pb1 = *(const uint4*)(brow1 + kn);
        }

        short8 afr[4], bfr[4];
        #pragma unroll
        for (int i=0;i<4;i++) {
            afr[i] = *(const short8*)(&lds_a[(wm*64 + i*16 + fm)*LDSP + q*8]);
            bfr[i] = *(const short8*)(&lds_b[(wn*64 + i*16 + fm)*LDSP + q*8]);
        }
        #pragma unroll
        for (int i=0;i<4;i++)
            #pragma unroll
            for (int j=0;j<4;j++)
                acc[i][j] = __builtin_amdgcn_mfma_f32_16x16x32_bf16(afr[i], bfr[j], acc[i][j], 0,0,0);
    }

    const int crow_base = tile_m + wm*64;
    const int ccol_base = tile_n + wn*64;
    #pragma unroll
    for (int i=0;i<4;i++) {
        #pragma unroll
        for (int j=0;j<4;j++) {
            int c  = ccol_base + j*16 + fm;
            float bb = bias[c];
            #pragma unroll
            for (int rg=0; rg<4; rg++) {
                int r = crow_base + i*16 + q*4 + rg;
                if (r < M) {
                    float v = acc[i][j][rg] + bb;
                    if (relu) v = fmaxf(v, 0.f);
                    C[(size_t)r*ldc + c] = f2bf(v);
                }
            }
        }
    }
}

__global__ __launch_bounds__(256) void gemm_bt(const __hip_bfloat16* __restrict__ A, int lda,
                                               const __hip_bfloat16* __restrict__ Bt,
                                               const float* __restrict__ bias,
                                               __hip_bfloat16* __restrict__ C, int ldc,
                                               int M, int K, int relu)
{
    __shared__ __align__(16) __hip_bfloat16 lds_a[128*LDSP];
    __shared__ __align__(16) __hip_bfloat16 lds_b[128*LDSP];
    gemm_bt_body(A, lda, Bt, bias, C, ldc, M, K, relu,
                 blockIdx.x*128, blockIdx.y*128, lds_a, lds_b);
}

// two independent GEMMs (same M=N_NODES, K=256, N=768) in one dispatch:
// blockIdx.y in [0,6) -> problem 0 (A0->C0), [6,12) -> problem 1 (A1->C1)
__global__ __launch_bounds__(256) void gemm_bt_dual(const __hip_bfloat16* __restrict__ A0,
                                                    const __hip_bfloat16* __restrict__ A1,
                                                    const __hip_bfloat16* __restrict__ Bt0,
                                                    const __hip_bfloat16* __restrict__ Bt1,
                                                    const float* __restrict__ bias0,
                                                    const float* __restrict__ bias1,
                                                    __hip_bfloat16* __restrict__ C0,
                                                    __hip_bfloat16* __restrict__ C1)
{
    __shared__ __align__(16) __hip_bfloat16 lds_a[128*LDSP];
    __shared__ __align__(16) __hip_bfloat16 lds_b[128*LDSP];
    int which = blockIdx.y >= 6;
    int ty    = which ? (blockIdx.y - 6) : blockIdx.y;
    gemm_bt_body(which ? A1 : A0, 256,
                 which ? Bt1 : Bt0,
                 which ? bias1 : bias0,
                 which ? C1 : C0, 768,
                 N_NODES, 256, 0,
                 blockIdx.x*128, ty*128, lds_a, lds_b);
}

// ---------------- attention scores: ONE WAVE PER NODE ----------------
__global__ __launch_bounds__(256) void score_kernel(const __hip_bfloat16* __restrict__ qkvs,
                                                    const int* __restrict__ row_ptr,
                                                    const int* __restrict__ csr_src,
                                                    float* __restrict__ score)
{
    int i = blockIdx.x*4 + (threadIdx.x >> 6);
    int lane = threadIdx.x & 63;
    int h = lane >> 4, d4 = lane & 15;
    int e0 = row_ptr[i*R_REL], e1 = row_ptr[i*R_REL + R_REL];
    ushort4 qv = *(const ushort4*)(qkvs + (size_t)i*1024 + lane*4);
    float qx=bfbits2f(qv.x), qy=bfbits2f(qv.y), qz=bfbits2f(qv.z), qw=bfbits2f(qv.w);
    float* sp = score + (size_t)h*E_EDGES;
    int j = e0;
    for (; j+2 <= e1; j += 2) {
        int s0 = csr_src[j], s1 = csr_src[j+1];
        ushort4 k0 = *(const ushort4*)(qkvs + (size_t)s0*1024 + 256 + lane*4);
        ushort4 k1 = *(const ushort4*)(qkvs + (size_t)s1*1024 + 256 + lane*4);
        float d0 = qx*bfbits2f(k0.x)+qy*bfbits2f(k0.y)+qz*bfbits2f(k0.z)+qw*bfbits2f(k0.w);
        float d1 = qx*bfbits2f(k1.x)+qy*bfbits2f(k1.y)+qz*bfbits2f(k1.z)+qw*bfbits2f(k1.w);
        #pragma unroll
        for (int o=1;o<16;o<<=1){ d0 += __shfl_xor(d0,o,64); d1 += __shfl_xor(d1,o,64); }
        if (d4 == 0) { sp[j] = d0*0.125f; sp[j+1] = d1*0.125f; }
    }
    for (; j < e1; j++) {
        int s0 = csr_src[j];
        ushort4 k0 = *(const ushort4*)(qkvs + (size_t)s0*1024 + 256 + lane*4);
        float d0 = qx*bfbits2f(k0.x)+qy*bfbits2f(k0.y)+qz*bfbits2f(k0.z)+qw*bfbits2f(k0.w);
        #pragma unroll
        for (int o=1;o<16;o<<=1) d0 += __shfl_xor(d0,o,64);
        if (d4 == 0) sp[j] = d0*0.125f;
    }
}

// ---------------- attention aggregate: ONE WAVE PER NODE, all 4 heads ----------------
__global__ __launch_bounds__(256) void attn_agg_kernel(const __hip_bfloat16* __restrict__ qkvs,
                                                       const float* __restrict__ score,
                                                       const int* __restrict__ row_ptr,
                                                       const int* __restrict__ csr_src,
                                                       __hip_bfloat16* __restrict__ hatt)
{
    int i = blockIdx.x*4 + (threadIdx.x >> 6);   // node (4 nodes per block)
    int lane = threadIdx.x & 63;
    int h  = lane >> 4;
    int d4 = lane & 15;
    int e0 = row_ptr[i*R_REL], e1 = row_ptr[i*R_REL + R_REL];
    int deg = e1 - e0;
    const float* sp = score + (size_t)h*E_EDGES + e0;

    // pass 1: per-head max
    float m = -1e30f;
    for (int j = d4; j < deg; j += 16) m = fmaxf(m, sp[j]);
    #pragma unroll
    for (int o=1;o<16;o<<=1) m = fmaxf(m, __shfl_xor(m, o, 64));

    // pass 2: per-head denom
    float ssum = 0.f;
    for (int j = d4; j < deg; j += 16) ssum += __expf(sp[j] - m);
    #pragma unroll
    for (int o=1;o<16;o<<=1) ssum += __shfl_xor(ssum, o, 64);
    float inv = 1.f / fmaxf(ssum, 1e-16f);

    // pass 3: all lanes walk all edges (unroll 4), no cross-lane reduction
    float ax=0.f, ay=0.f, az=0.f, aw=0.f;
    int j = 0;
    for (; j+4 <= deg; j += 4) {
        int s0=csr_src[e0+j], s1=csr_src[e0+j+1], s2=csr_src[e0+j+2], s3=csr_src[e0+j+3];
        float w0 = __expf(sp[j]   - m) * inv;
        float w1 = __expf(sp[j+1] - m) * inv;
        float w2 = __expf(sp[j+2] - m) * inv;
        float w3 = __expf(sp[j+3] - m) * inv;
        ushort4 u0 = *(const ushort4*)(qkvs + (size_t)s0*1024 + 512 + lane*4);
        ushort4 u1 = *(const ushort4*)(qkvs + (size_t)s1*1024 + 512 + lane*4);
        ushort4 u2 = *(const ushort4*)(qkvs + (size_t)s2*1024 + 512 + lane*4);
        ushort4 u3 = *(const ushort4*)(qkvs + (size_t)s3*1024 + 512 + lane*4);
        ax += w0*bfbits2f(u0.x) + w1*bfbits2f(u1.x) + w2*bfbits2f(u2.x) + w3*bfbits2f(u3.x);
        ay += w0*bfbits2f(u0.y) + w1*bfbits2f(u1.y) + w2*bfbits2f(u2.y) + w3*bfbits2f(u3.y);
        az += w0*bfbits2f(u0.z) + w1*bfbits2f(u1.z) + w2*bfbits2f(u2.z) + w3*bfbits2f(u3.z);
        aw += w0*bfbits2f(u0.w) + w1*bfbits2f(u1.w) + w2*bfbits2f(u2.w) + w3*bfbits2f(u3.w);
    }
    for (; j < deg; j++) {
        int s = csr_src[e0+j];
        float w = __expf(sp[j] - m) * inv;
        ushort4 u = *(const ushort4*)(qkvs + (size_t)s*1024 + 512 + lane*4);
        ax += w*bfbits2f(u.x); ay += w*bfbits2f(u.y);
        az += w*bfbits2f(u.z); aw += w*bfbits2f(u.w);
    }
    ushort4 sk = *(const ushort4*)(qkvs + (size_t)i*1024 + 768 + lane*4);
    uint2 w;
    w.x = pack_bf2(ax + bfbits2f(sk.x), ay + bfbits2f(sk.y));
    w.y = pack_bf2(az + bfbits2f(sk.z), aw + bfbits2f(sk.w));
    *(uint2*)(hatt + (size_t)i*256 + lane*4) = w;
}

// ---------------- GRU elementwise (bf16 gates, fp32 math, fp32 out) ----------------
__global__ void gru_kernel(const __hip_bfloat16* __restrict__ gi,
                           const __hip_bfloat16* __restrict__ gh,
                           const float* __restrict__ hprev,
                           float* __restrict__ out)
{
    int idx = blockIdx.x*256 + threadIdx.x;
    if (idx >= N_NODES*HIDF) return;
    int i = idx / HIDF, c = idx % HIDF;
    size_t gb = (size_t)i*768;
    float ir = bf2f(gi[gb + c]), iz = bf2f(gi[gb + 256 + c]), in = bf2f(gi[gb + 512 + c]);
    float hr = bf2f(gh[gb + c]), hz = bf2f(gh[gb + 256 + c]), hn = bf2f(gh[gb + 512 + c]);
    float r = 1.f/(1.f + __expf(-(ir+hr)));
    float z = 1.f/(1.f + __expf(-(iz+hz)));
    float n = tanhf(in + r*hn);
    float h = hprev[idx];
    out[idx] = (1.f - z)*n + z*h;
}

// ---------------- launch ----------------
// Inputs fp32 (verified round 3); bf16 internally for MFMA. Workspace ~107 MB:
//   P1 (25.6 MB):  A1 -> h2 -> hatt
//   P2 (61.4 MB):  A2 -> qkvs -> (gi | gh)   (gi at 0, gh at +N*768 elements)
extern "C" void kernel_launch(void* const* d_in, const int* in_sizes, int n_in,
                              void* d_out, int out_size, void* d_ws, size_t ws_size,
                              hipStream_t stream)
{
    const float* x       = (const float*)d_in[0];
    const int* edge_index= (const int*)d_in[1];
    const int* edge_type = (const int*)d_in[2];
    const float* hprev   = (const float*)d_in[3];
    const float* W1      = (const float*)d_in[4];
    const float* root1   = (const float*)d_in[5];
    const float* b1      = (const float*)d_in[6];
    const float* W2      = (const float*)d_in[7];
    const float* root2   = (const float*)d_in[8];
    const float* b2      = (const float*)d_in[9];
    const float* Wq      = (const float*)d_in[10];
    const float* bq      = (const float*)d_in[11];
    const float* Wk      = (const float*)d_in[12];
    const float* bk      = (const float*)d_in[13];
    const float* Wv      = (const float*)d_in[14];
    const float* bv      = (const float*)d_in[15];
    const float* Wskip   = (const float*)d_in[16];
    const float* bskip   = (const float*)d_in[17];
    const float* W_ih    = (const float*)d_in[18];
    const float* b_ih    = (const float*)d_in[19];
    const float* W_hh    = (const float*)d_in[20];
    const float* b_hh    = (const float*)d_in[21];

    char* ws = (char*)d_ws;
    size_t off = 0;
    auto take = [&](size_t bytes)->char* {
        char* p = ws + off;
        off = (off + bytes + 255) & ~(size_t)255;
        return p;
    };
    int* cnt        = (int*)take((size_t)NRKEYS*4);
    int* row_ptr    = (int*)take((size_t)(NRKEYS+1)*4);
    int* cursor     = (int*)take((size_t)NRKEYS*4);
    int* csr_src    = (int*)take((size_t)E_EDGES*4);
    int* blocksum   = (int*)take((size_t)SCAN_BLOCKS*4);
    int* blockoff   = (int*)take((size_t)(SCAN_BLOCKS+1)*4);
    float* score    = (float*)take((size_t)R_REL*E_EDGES*4);   // [HEADS][E], CSR-position-indexed
    __hip_bfloat16* B1t   = (__hip_bfloat16*)take((size_t)256*640*2);
    __hip_bfloat16* B2t   = (__hip_bfloat16*)take((size_t)256*1280*2);
    __hip_bfloat16* B3t   = (__hip_bfloat16*)take((size_t)1024*256*2);
    __hip_bfloat16* Biht  = (__hip_bfloat16*)take((size_t)768*256*2);
    __hip_bfloat16* Bhht  = (__hip_bfloat16*)take((size_t)768*256*2);
    float*          bias3 = (float*)take((size_t)1024*4);
    __hip_bfloat16* hprev_bf = (__hip_bfloat16*)take((size_t)N_NODES*256*2);
    // P1: max(A1 N*640, h2 N*256, hatt N*256) bf16
    char* P1 = take((size_t)N_NODES*640*2);
    // P2: max(A2 N*1280, qkvs N*1024, gi+gh N*1536) bf16
    char* P2 = take((size_t)N_NODES*1536*2);

    __hip_bfloat16* A1   = (__hip_bfloat16*)P1;   // [N,640]  dead after gemm1
    __hip_bfloat16* h2   = (__hip_bfloat16*)P1;   // [N,256]  dead after gemm3
    __hip_bfloat16* hatt = (__hip_bfloat16*)P1;   // [N,256]  read by gemm45
    __hip_bfloat16* A2   = (__hip_bfloat16*)P2;   // [N,1280] dead after gemm2
    __hip_bfloat16* qkvs = (__hip_bfloat16*)P2;   // [N,1024] dead after attn_agg
    __hip_bfloat16* gi   = (__hip_bfloat16*)P2;                          // [N,768]
    __hip_bfloat16* gh   = (__hip_bfloat16*)(P2 + (size_t)N_NODES*768*2); // [N,768]

    hipMemsetAsync(cnt, 0, (size_t)NRKEYS*4, stream);
    count_kernel<<<(E_EDGES+255)/256, 256, 0, stream>>>(edge_index, edge_type, cnt);
    scan_reduce_kernel<<<SCAN_BLOCKS, 1024, 0, stream>>>(cnt, blocksum);
    scan_sums_kernel<<<1, 128, 0, stream>>>(blocksum, blockoff);
    scan_apply_kernel<<<SCAN_BLOCKS, 1024, 0, stream>>>(cnt, blockoff, row_ptr, cursor);
    fill_kernel<<<(E_EDGES+255)/256, 256, 0, stream>>>(edge_index, edge_type, cursor, csr_src);

    make_b1t<<<(256*640+255)/256, 256, 0, stream>>>(root1, W1, B1t);
    make_b2t<<<(256*1280+255)/256, 256, 0, stream>>>(root2, W2, B2t);
    make_b3t<<<(1024*256+255)/256, 256, 0, stream>>>(Wq, Wk, Wv, Wskip, bq, bk, bv, bskip, B3t, bias3);
    cvt_f32_bf16<<<(768*256+255)/256, 256, 0, stream>>>(W_ih, Biht, 768*256);
    cvt_f32_bf16<<<(768*256+255)/256, 256, 0, stream>>>(W_hh, Bhht, 768*256);
    cvt_f32_bf16<<<(N_NODES*256+255)/256, 256, 0, stream>>>(hprev, hprev_bf, N_NODES*256);

    // one wave per (node,rel) key; block covers node's 4 rels
    agg1_kernel<<<NRKEYS/4, 256, 0, stream>>>(x, row_ptr, csr_src, A1);

    dim3 g12(157, 2);
    // h1 = relu(A1 * B1) written into A2 cols 0..255 (ldc=1280)
    gemm_bt<<<g12, 256, 0, stream>>>(A1, 640, B1t, b1, A2, 1280, N_NODES, 640, 1);

    agg2_kernel<<<NRKEYS/4, 256, 0, stream>>>(row_ptr, csr_src, A2);

    // h2 overwrites A1 (dead) in P1
    gemm_bt<<<g12, 256, 0, stream>>>(A2, 1280, B2t, b2, h2, 256, N_NODES, 1280, 1);

    // qkvs overwrites A2 (dead) in P2
    dim3 g3(157, 8);
    gemm_bt<<<g3, 256, 0, stream>>>(h2, 256, B3t, bias3, qkvs, 1024, N_NODES, 256, 0);

    // attention: one-wave-per-node scores, then one-wave-per-node aggregate
    score_kernel<<<N_NODES/4, 256, 0, stream>>>(qkvs, row_ptr, csr_src, score);
    attn_agg_kernel<<<N_NODES/4, 256, 0, stream>>>(qkvs, score, row_ptr, csr_src, hatt);

    // fused GRU gate GEMMs: gi = hatt*W_ih^T + b_ih ; gh = hprev*W_hh^T + b_hh
    dim3 g45(157, 12);
    gemm_bt_dual<<<g45, 256, 0, stream>>>(hatt, hprev_bf, Biht, Bhht, b_ih, b_hh, gi, gh);

    gru_kernel<<<(N_NODES*HIDF+255)/256, 256, 0, stream>>>(gi, gh, hprev, (float*)d_out);
}